// Round 9
// baseline (929.796 us; speedup 1.0000x reference)
//
#include <hip/hip_runtime.h>
#include <hip/hip_bf16.h>

#define ND 128
#define ED 128
#define NIN 128
#define EIN 291
#define KPAD 320   // EIN padded to multiple of 32
#define HH 64
#define TM 32      // nodes per block in node-embed / edges per block in classify
#define TS 64      // edges per block in edge_step
#define GSE 768    // grid blocks for edge_embed (3 per CU)
#define MAXGE 3    // max 64-edge tiles per edge_embed block

typedef __attribute__((ext_vector_type(8))) short short8;
typedef __attribute__((ext_vector_type(4))) float float4_;

__device__ __forceinline__ unsigned short f2bf(float f)
{
    union { float f; unsigned u; } v; v.f = f;
    unsigned u = v.u;
    unsigned r = (u + 0x7FFFu + ((u >> 16) & 1u)) >> 16;  // RNE
    return (unsigned short)r;
}
__device__ __forceinline__ float bf2f(unsigned short s)
{
    union { unsigned u; float f; } v; v.u = ((unsigned)s) << 16;
    return v.f;
}

// Stage T N-tiles x KC k-chunks of B (layout [col][K], bf16) into LDS in MFMA
// FRAGMENT ORDER (used by node/edge embed only now).
template<int T, int KC, int K>
__device__ __forceinline__ void stage_frags(const unsigned short* __restrict__ src,
                                            unsigned short* __restrict__ wreg,
                                            int t, int k0)
{
    constexpr int TOT = T * KC * 64;
#pragma unroll
    for (int it = 0; it < TOT / 256; it++) {
        int idx = it * 256 + t;
        int f = idx >> 6, l = idx & 63;
        int col = (f / KC) * 16 + (l & 15);
        int k = (f % KC) * 32 + ((l >> 4) * 8);
        *(short8*)&wreg[idx * 8] = *(const short8*)&src[(size_t)col * K + k0 + k];
    }
}
#define FRAG(wreg, f, lane) (*(const short8*)&(wreg)[(((f) << 6) + (lane)) * 8])
// Global fragment-ordered B access: frag f, lane -> 16B
#define GFRAG(wp, f, lane) (*(const short8*)&(wp)[(((f) << 6) + (lane)) * 8])

// Zero a buffer (16B granules).
__global__ __launch_bounds__(256) void zero_k(float* __restrict__ p, int n4)
{
    int idx = blockIdx.x * 256 + threadIdx.x;
    if (idx < n4) ((float4*)p)[idx] = make_float4(0.f, 0.f, 0.f, 0.f);
}

// ---- CSR build (once per launch; edge_index is constant across the 4 steps) ----
__global__ __launch_bounds__(256) void hist_k(const int* __restrict__ tgti,
                                              int* __restrict__ deg, int E)
{
    int e = blockIdx.x * 256 + threadIdx.x;
    if (e < E) atomicAdd(&deg[tgti[e]], 1);
}

// Single-block exclusive scan over deg[0..N) -> row_ptr & cursor.
__global__ __launch_bounds__(256) void scan_k(const int* __restrict__ deg,
                                              int* __restrict__ row_ptr,
                                              int* __restrict__ cursor, int N, int E)
{
    __shared__ int part[256];
    const int t = threadIdx.x;
    const int chunk = (N + 255) / 256;
    const int base = t * chunk;
    int s = 0;
    for (int k = 0; k < chunk; k++) { int idx = base + k; if (idx < N) s += deg[idx]; }
    part[t] = s;
    __syncthreads();
    for (int off = 1; off < 256; off <<= 1) {
        int v = (t >= off) ? part[t - off] : 0;
        __syncthreads();
        part[t] += v;
        __syncthreads();
    }
    int run = (t == 0) ? 0 : part[t - 1];
    for (int k = 0; k < chunk; k++) {
        int idx = base + k;
        if (idx < N) { row_ptr[idx] = run; cursor[idx] = run; run += deg[idx]; }
    }
    if (t == 255) row_ptr[N] = E;
}

__global__ __launch_bounds__(256) void scatter_k(const int* __restrict__ tgti,
                                                 int* __restrict__ cursor,
                                                 int* __restrict__ csr_eid, int E)
{
    int e = blockIdx.x * 256 + threadIdx.x;
    if (e < E) {
        int p = atomicAdd(&cursor[tgti[e]], 1);
        csr_eid[p] = e;
    }
}

// Segment-sum of messages at target nodes (coalesced 256B reads, no atomics).
__global__ __launch_bounds__(256) void agg_k(const int* __restrict__ row_ptr,
                                             const int* __restrict__ csr_eid,
                                             const unsigned short* __restrict__ msg,
                                             unsigned short* __restrict__ nf_bf, int N)
{
    int n = blockIdx.x * 2 + (threadIdx.x >> 7);
    int c = threadIdx.x & 127;
    if (n >= N) return;
    int beg = row_ptr[n], end = row_ptr[n + 1];
    float acc = 0.f;
    for (int k = beg; k < end; k++) {
        int e = csr_eid[k];
        acc += bf2f(msg[(size_t)e * ND + c]);
    }
    nf_bf[(size_t)n * ND + c] = f2bf(acc);
}

// One-time weight prep. MPN weights (w0F,w1F,wmF) FRAGMENT-ORDERED in
// global: frag f, lane l, elem j -> W[k][col] with col=(f/KC)*16+(l&15),
// k=(f%KC)*32+(l>>4)*8+j. Embed/classify weights stay [col][K].
__global__ __launch_bounds__(256) void wprep_k(
    const float* __restrict__ mew0, const float* __restrict__ mew1, const float* __restrict__ mnw0,
    const float* __restrict__ eew0, const float* __restrict__ eew1, const float* __restrict__ cw0,
    const float* __restrict__ new0, const float* __restrict__ new1,
    unsigned short* __restrict__ w0F, unsigned short* __restrict__ w1F,
    unsigned short* __restrict__ wmF, unsigned short* __restrict__ w0eT,
    unsigned short* __restrict__ w1eT, unsigned short* __restrict__ cw0T,
    unsigned short* __restrict__ w0nT, unsigned short* __restrict__ w1nT)
{
    int idx = blockIdx.x * 256 + threadIdx.x;
    if (idx < 49152) {
        // w0F: mew0 [768][64], KC=24
        int j = idx & 7, l = (idx >> 3) & 63, f = idx >> 9;
        int col = (f / 24) * 16 + (l & 15);
        int k = (f % 24) * 32 + ((l >> 4) * 8) + j;
        w0F[idx] = f2bf(mew0[k * 64 + col]);
    } else if (idx < 57344) {
        // w1F: mew1 [64][128], KC=2
        int i2 = idx - 49152;
        int j = i2 & 7, l = (i2 >> 3) & 63, f = i2 >> 9;
        int col = (f / 2) * 16 + (l & 15);
        int k = (f % 2) * 32 + ((l >> 4) * 8) + j;
        w1F[i2] = f2bf(mew1[k * 128 + col]);
    } else if (idx < 106496) {
        // wmF: mnw0 [384][128], KC=12
        int i2 = idx - 57344;
        int j = i2 & 7, l = (i2 >> 3) & 63, f = i2 >> 9;
        int col = (f / 12) * 16 + (l & 15);
        int k = (f % 12) * 32 + ((l >> 4) * 8) + j;
        wmF[i2] = f2bf(mnw0[k * 128 + col]);
    } else if (idx < 126976) {
        int j = idx - 106496; int c = j / KPAD, k = j % KPAD;
        w0eT[j] = (k < EIN) ? f2bf(eew0[k * 64 + c]) : (unsigned short)0;
    } else if (idx < 135168) {
        int j = idx - 126976; int c = j / 64, k = j % 64;
        w1eT[j] = f2bf(eew1[k * 128 + c]);
    } else if (idx < 143360) {
        int j = idx - 135168; int c = j / 128, k = j % 128;
        cw0T[j] = f2bf(cw0[k * 64 + c]);
    } else if (idx < 159744) {
        int j = idx - 143360; int c = j / 128, k = j % 128;
        w0nT[j] = f2bf(new0[k * 128 + c]);
    } else if (idx < 176128) {
        int j = idx - 159744; int c = j / 128, k = j % 128;
        w1nT[j] = f2bf(new1[k * 128 + c]);
    }
}

// MFMA node embed: 32 nodes/block (unchanged).
__global__ __launch_bounds__(256) void node_embed_k(
    const float* __restrict__ x,
    const unsigned short* __restrict__ w0nT, const float* __restrict__ b0,
    const unsigned short* __restrict__ w1nT, const float* __restrict__ b1,
    unsigned short* __restrict__ nf0_bf, unsigned short* __restrict__ nf_bf, int N)
{
    const int t = threadIdx.x;
    const int n0 = blockIdx.x * TM;
    __shared__ unsigned short wreg[8192];
    __shared__ unsigned short xin[TM][130];
    __shared__ unsigned short h_bf[TM][130];

#pragma unroll
    for (int it = 0; it < 4; it++) {
        int idx = it * 256 + t;
        int r = idx >> 5, c4 = idx & 31;
        int node = n0 + r; if (node >= N) node = N - 1;
        float4 v = *(const float4*)(x + (size_t)node * NIN + c4 * 4);
        unsigned lo = (unsigned)f2bf(v.x) | ((unsigned)f2bf(v.y) << 16);
        unsigned hi = (unsigned)f2bf(v.z) | ((unsigned)f2bf(v.w) << 16);
        *(uint2*)&xin[r][c4 * 4] = make_uint2(lo, hi);
    }

    const int w = t >> 6, lane = t & 63, quad = lane >> 4, n16 = lane & 15;
    const int m = w & 1, nh = w >> 1;

    float4_ acc[4];
#pragma unroll
    for (int q = 0; q < 4; q++) acc[q] = (float4_){0.f, 0.f, 0.f, 0.f};
#pragma unroll
    for (int hf = 0; hf < 2; hf++) {
        stage_frags<8, 2, 128>(w0nT, wreg, t, hf * 64);
        __syncthreads();
#pragma unroll
        for (int kc = 0; kc < 2; kc++) {
            short8 a = *(const short8*)&xin[m * 16 + n16][hf * 64 + kc * 32 + quad * 8];
#pragma unroll
            for (int tt = 0; tt < 4; tt++) {
                short8 b = FRAG(wreg, (nh * 4 + tt) * 2 + kc, lane);
                acc[tt] = __builtin_amdgcn_mfma_f32_16x16x32_bf16(a, b, acc[tt], 0, 0, 0);
            }
        }
        __syncthreads();
    }
#pragma unroll
    for (int tt = 0; tt < 4; tt++) {
        int c = nh * 64 + tt * 16 + n16;
        float bias = b0[c];
#pragma unroll
        for (int r4 = 0; r4 < 4; r4++)
            h_bf[m * 16 + quad * 4 + r4][c] = f2bf(fmaxf(acc[tt][r4] + bias, 0.f));
    }
    __syncthreads();

    float4_ acc2[4];
#pragma unroll
    for (int q = 0; q < 4; q++) acc2[q] = (float4_){0.f, 0.f, 0.f, 0.f};
#pragma unroll
    for (int hf = 0; hf < 2; hf++) {
        stage_frags<8, 2, 128>(w1nT, wreg, t, hf * 64);
        __syncthreads();
#pragma unroll
        for (int kc = 0; kc < 2; kc++) {
            short8 a = *(const short8*)&h_bf[m * 16 + n16][hf * 64 + kc * 32 + quad * 8];
#pragma unroll
            for (int tt = 0; tt < 4; tt++) {
                short8 b = FRAG(wreg, (nh * 4 + tt) * 2 + kc, lane);
                acc2[tt] = __builtin_amdgcn_mfma_f32_16x16x32_bf16(a, b, acc2[tt], 0, 0, 0);
            }
        }
        __syncthreads();
    }
#pragma unroll
    for (int tt = 0; tt < 4; tt++) {
        int c = nh * 64 + tt * 16 + n16;
        float bias = b1[c];
#pragma unroll
        for (int r4 = 0; r4 < 4; r4++) {
            int row = m * 16 + quad * 4 + r4;
            int node = n0 + row;
            if (node < N) {
                unsigned short v = f2bf(acc2[tt][r4] + bias);
                nf0_bf[(size_t)node * ND + c] = v;
                nf_bf[(size_t)node * ND + c] = v;
            }
        }
    }
}

// MFMA edge embed v2 (unchanged): 64 edges/block, 4 waves, grid-stride tiles.
__global__ __launch_bounds__(256, 3) void edge_embed_k(
    const float* __restrict__ ea,
    const unsigned short* __restrict__ w0eT, const float* __restrict__ b0,
    const unsigned short* __restrict__ w1eT, const float* __restrict__ b1,
    unsigned short* __restrict__ ef0_bf, unsigned short* __restrict__ ef_bf,
    int E, int ntiles)
{
    const int t = threadIdx.x;
    __shared__ unsigned short w0reg[10240];   // 20KB: one K-half (T=4, KC=5)
    __shared__ unsigned short w1reg[8192];    // 16KB: w1e full (T=8, KC=2)
    __shared__ unsigned short hsl[4][16 * 66];

    const int w = t >> 6, lane = t & 63, quad = lane >> 4, n16 = lane & 15;

    stage_frags<8, 2, 64>(w1eT, w1reg, t, 0);   // covered by first barrier below

    int ng = 0;
    int tile[MAXGE];
#pragma unroll
    for (int g = 0; g < MAXGE; g++) {
        int tl = blockIdx.x + g * GSE;
        if (tl < ntiles) { tile[g] = tl; ng = g + 1; }
        else tile[g] = 0;
    }

    float4_ accL[MAXGE][4];
#pragma unroll
    for (int g = 0; g < MAXGE; g++)
#pragma unroll
        for (int q = 0; q < 4; q++) accL[g][q] = (float4_){0.f, 0.f, 0.f, 0.f};

#pragma unroll
    for (int hf = 0; hf < 2; hf++) {
        __syncthreads();
        stage_frags<4, 5, KPAD>(w0eT, w0reg, t, hf * 160);
        __syncthreads();
#pragma unroll
        for (int g = 0; g < MAXGE; g++) {
            if (g < ng) {
                int e = tile[g] * 64 + w * 16 + n16; if (e >= E) e = E - 1;
                const float* src = ea + (size_t)e * EIN;
#pragma unroll
                for (int kc = 0; kc < 5; kc++) {
                    int k = hf * 160 + kc * 32 + quad * 8;
                    union { short8 s; uint4 u; } av;
                    if (k + 8 <= EIN) {
                        float4 v0 = *(const float4*)(src + k);
                        float4 v1 = *(const float4*)(src + k + 4);
                        av.u.x = (unsigned)f2bf(v0.x) | ((unsigned)f2bf(v0.y) << 16);
                        av.u.y = (unsigned)f2bf(v0.z) | ((unsigned)f2bf(v0.w) << 16);
                        av.u.z = (unsigned)f2bf(v1.x) | ((unsigned)f2bf(v1.y) << 16);
                        av.u.w = (unsigned)f2bf(v1.z) | ((unsigned)f2bf(v1.w) << 16);
                    } else {
                        unsigned short vv[8];
#pragma unroll
                        for (int j = 0; j < 8; j++)
                            vv[j] = (k + j < EIN) ? f2bf(src[k + j]) : (unsigned short)0;
                        av.u.x = (unsigned)vv[0] | ((unsigned)vv[1] << 16);
                        av.u.y = (unsigned)vv[2] | ((unsigned)vv[3] << 16);
                        av.u.z = (unsigned)vv[4] | ((unsigned)vv[5] << 16);
                        av.u.w = (unsigned)vv[6] | ((unsigned)vv[7] << 16);
                    }
#pragma unroll
                    for (int tt = 0; tt < 4; tt++) {
                        short8 b = FRAG(w0reg, tt * 5 + kc, lane);
                        accL[g][tt] = __builtin_amdgcn_mfma_f32_16x16x32_bf16(av.s, b, accL[g][tt], 0, 0, 0);
                    }
                }
            }
        }
    }

    // epilogue per tile: bias+ReLU -> per-wave hsl (C->A transform), then L2
#pragma unroll
    for (int g = 0; g < MAXGE; g++) {
        if (g < ng) {
#pragma unroll
            for (int tt = 0; tt < 4; tt++) {
                int c = tt * 16 + n16;
                float bias = b0[c];
#pragma unroll
                for (int r4 = 0; r4 < 4; r4++)
                    hsl[w][(quad * 4 + r4) * 66 + c] = f2bf(fmaxf(accL[g][tt][r4] + bias, 0.f));
            }
            float4_ acc2[8];
#pragma unroll
            for (int q = 0; q < 8; q++) acc2[q] = (float4_){0.f, 0.f, 0.f, 0.f};
#pragma unroll
            for (int kc = 0; kc < 2; kc++) {
                short8 a2 = *(const short8*)&hsl[w][n16 * 66 + kc * 32 + quad * 8];
#pragma unroll
                for (int tt = 0; tt < 8; tt++)
                    acc2[tt] = __builtin_amdgcn_mfma_f32_16x16x32_bf16(
                        a2, FRAG(w1reg, tt * 2 + kc, lane), acc2[tt], 0, 0, 0);
            }
#pragma unroll
            for (int tt = 0; tt < 8; tt++) {
                int c = tt * 16 + n16;
                float bias = b1[c];
#pragma unroll
                for (int r4 = 0; r4 < 4; r4++) {
                    int e = tile[g] * 64 + w * 16 + quad * 4 + r4;
                    if (e < E) {
                        unsigned short v = f2bf(acc2[tt][r4] + bias);  // no ReLU
                        ef0_bf[(size_t)e * ED + c] = v;
                        ef_bf[(size_t)e * ED + c] = v;
                    }
                }
            }
        }
    }
}

// MFMA MPN step v5 — BARRIER-FREE, spill-fixed. Same as v4 but
// __launch_bounds__(256,3): the (256,4) unified VGPR+AGPR cap of 128/wave
// forced ~32 regs of accumulator spill to scratch (R8: +52MB WRITE_SIZE,
// +55us). 3 blocks/CU still gives 12 independent barrier-free waves.
__global__ __launch_bounds__(256, 3) void edge_step_k(
    const int* __restrict__ srcj, const int* __restrict__ tgti,
    const unsigned short* __restrict__ nf0_bf, const unsigned short* __restrict__ nf_bf,
    const unsigned short* __restrict__ ef0_bf, unsigned short* __restrict__ ef_bf,
    unsigned short* __restrict__ msg,
    const unsigned short* __restrict__ w0F, const float* __restrict__ meb0,
    const unsigned short* __restrict__ w1F, const float* __restrict__ meb1,
    const unsigned short* __restrict__ wmF, const float* __restrict__ mnb0,
    int E, int wmsg)
{
    const int t = threadIdx.x;
    const int e0 = blockIdx.x * TS;
    __shared__ unsigned short hef[4][2080];   // wave-private band: h(66) / efn(130)

    const int w = t >> 6, lane = t & 63, quad = lane >> 4, n16 = lane & 15;
    int ec = e0 + w * 16 + n16; if (ec >= E) ec = E - 1;
    const int ti = tgti[ec], sj = srcj[ec];

    const unsigned short* pA[6] = {
        nf0_bf + (size_t)ti * ND + quad * 8,
        nf_bf  + (size_t)ti * ND + quad * 8,
        nf0_bf + (size_t)sj * ND + quad * 8,
        nf_bf  + (size_t)sj * ND + quad * 8,
        ef0_bf + (size_t)ec * ED + quad * 8,
        ef_bf  + (size_t)ec * ED + quad * 8 };

    // ---- edge MLP L0: K=768 (KC=24), N=64 (T=4) ----
    float4_ accL[4];
#pragma unroll
    for (int q = 0; q < 4; q++) accL[q] = (float4_){0.f, 0.f, 0.f, 0.f};
#pragma unroll
    for (int kc = 0; kc < 24; kc++) {
        short8 a = *(const short8*)(pA[kc >> 2] + (kc & 3) * 32);
#pragma unroll
        for (int tt = 0; tt < 4; tt++) {
            short8 b = GFRAG(w0F, tt * 24 + kc, lane);
            accL[tt] = __builtin_amdgcn_mfma_f32_16x16x32_bf16(a, b, accL[tt], 0, 0, 0);
        }
    }

    // L0 epilogue -> h band (wave-private; in-wave LDS ordering, no barrier)
#pragma unroll
    for (int tt = 0; tt < 4; tt++) {
        int c = tt * 16 + n16;
        float bias = meb0[c];
#pragma unroll
        for (int r4 = 0; r4 < 4; r4++)
            hef[w][(quad * 4 + r4) * 66 + c] = f2bf(fmaxf(accL[tt][r4] + bias, 0.f));
    }

    // ---- edge MLP L1: K=64 (KC=2), N=128 (T=8) ----
    {
        float4_ acc[8];
#pragma unroll
        for (int q = 0; q < 8; q++) acc[q] = (float4_){0.f, 0.f, 0.f, 0.f};
#pragma unroll
        for (int kc = 0; kc < 2; kc++) {
            short8 a = *(const short8*)&hef[w][n16 * 66 + kc * 32 + quad * 8];
#pragma unroll
            for (int tt = 0; tt < 8; tt++) {
                short8 b = GFRAG(w1F, tt * 2 + kc, lane);
                acc[tt] = __builtin_amdgcn_mfma_f32_16x16x32_bf16(a, b, acc[tt], 0, 0, 0);
            }
        }
        // epilogue: efn overlays h in own-wave band (stride 130) + global ef store
#pragma unroll
        for (int tt = 0; tt < 8; tt++) {
            int c = tt * 16 + n16;
            float bias = meb1[c];
#pragma unroll
            for (int r4 = 0; r4 < 4; r4++) {
                int row = quad * 4 + r4;
                unsigned short v = f2bf(fmaxf(acc[tt][r4] + bias, 0.f));
                hef[w][row * 130 + c] = v;
                int e = e0 + w * 16 + row;
                if (e < E) ef_bf[(size_t)e * ED + c] = v;
            }
        }
    }

    // ---- node-message MLP: K=384 (KC=12), N=128 (T=8) ----
    // (skipped on the last step: final nf is never consumed)
    if (wmsg) {
        float4_ accM[8];
#pragma unroll
        for (int q = 0; q < 8; q++) accM[q] = (float4_){0.f, 0.f, 0.f, 0.f};
#pragma unroll
        for (int kc = 0; kc < 12; kc++) {
            short8 a;
            if (kc < 8) a = *(const short8*)(pA[kc >> 2] + (kc & 3) * 32);
            else        a = *(const short8*)&hef[w][n16 * 130 + (kc - 8) * 32 + quad * 8];
#pragma unroll
            for (int tt = 0; tt < 8; tt++) {
                short8 b = GFRAG(wmF, tt * 12 + kc, lane);
                accM[tt] = __builtin_amdgcn_mfma_f32_16x16x32_bf16(a, b, accM[tt], 0, 0, 0);
            }
        }
#pragma unroll
        for (int tt = 0; tt < 8; tt++) {
            int c = tt * 16 + n16;
            float bias = mnb0[c];
#pragma unroll
            for (int r4 = 0; r4 < 4; r4++) {
                int e = e0 + w * 16 + quad * 4 + r4;
                if (e < E)
                    msg[(size_t)e * ND + c] = f2bf(fmaxf(accM[tt][r4] + bias, 0.f));
            }
        }
    }
}

// classify (unchanged).
__global__ __launch_bounds__(256) void classify_k(
    const unsigned short* __restrict__ ef_bf,
    const unsigned short* __restrict__ cw0T, const float* __restrict__ cb0,
    const float* __restrict__ cw1, const float* __restrict__ cb1,
    const float* __restrict__ cw2, const float* __restrict__ cb2,
    float* __restrict__ out, int E)
{
    const int t = threadIdx.x;
    const int e0 = blockIdx.x * TM;
    __shared__ unsigned short h0_bf[TM][66];
    __shared__ float h1[TM][33];

    const int w = t >> 6, lane = t & 63, quad = lane >> 4, n16 = lane & 15;
    const int m = w & 1;
    const int erow = m * 16 + n16;
    int ec = e0 + erow; if (ec >= E) ec = E - 1;
    const unsigned short* pa = ef_bf + (size_t)ec * ED + quad * 8;

    {
        const int cb = (w >> 1) * 32;
        float4_ acc0 = {0.f, 0.f, 0.f, 0.f}, acc1 = acc0;
        const unsigned short* b0p = cw0T + (size_t)(cb + n16) * 128 + quad * 8;
        const unsigned short* b1p = b0p + (size_t)16 * 128;
#pragma unroll
        for (int kc = 0; kc < 4; kc++) {
            short8 a  = *(const short8*)(pa + kc * 32);
            short8 bb0 = *(const short8*)(b0p + kc * 32);
            short8 bb1 = *(const short8*)(b1p + kc * 32);
            acc0 = __builtin_amdgcn_mfma_f32_16x16x32_bf16(a, bb0, acc0, 0, 0, 0);
            acc1 = __builtin_amdgcn_mfma_f32_16x16x32_bf16(a, bb1, acc1, 0, 0, 0);
        }
#pragma unroll
        for (int t2 = 0; t2 < 2; t2++) {
            int c = cb + t2 * 16 + n16;
            float bias = cb0[c];
            float4_ ac = t2 ? acc1 : acc0;
#pragma unroll
            for (int r4 = 0; r4 < 4; r4++)
                h0_bf[m * 16 + quad * 4 + r4][c] = f2bf(fmaxf(ac[r4] + bias, 0.f));
        }
    }
    __syncthreads();

    {
        int c = t & 31;
        int rbase = (t >> 5) * 4;
#pragma unroll
        for (int q = 0; q < 4; q++) {
            int r = rbase + q;
            float acc = cb1[c];
#pragma unroll 8
            for (int k = 0; k < 64; k++) acc += bf2f(h0_bf[r][k]) * cw1[k * 32 + c];
            h1[r][c] = fmaxf(acc, 0.f);
        }
    }
    __syncthreads();

    if (t < TM) {
        int e = e0 + t;
        if (e < E) {
            float a = cb2[0];
#pragma unroll
            for (int k = 0; k < 32; k++) a += h1[t][k] * cw2[k];
            out[e] = a;
        }
    }
}

extern "C" void kernel_launch(void* const* d_in, const int* in_sizes, int n_in,
                              void* d_out, int out_size, void* d_ws, size_t ws_size,
                              hipStream_t stream)
{
    const float* x    = (const float*)d_in[0];
    const float* ea   = (const float*)d_in[1];
    const int*   eidx = (const int*)d_in[2];
    const float* new0 = (const float*)d_in[3];  const float* neb0 = (const float*)d_in[4];
    const float* new1 = (const float*)d_in[5];  const float* neb1 = (const float*)d_in[6];
    const float* eew0 = (const float*)d_in[7];  const float* eeb0 = (const float*)d_in[8];
    const float* eew1 = (const float*)d_in[9];  const float* eeb1 = (const float*)d_in[10];
    const float* mew0 = (const float*)d_in[11]; const float* meb0 = (const float*)d_in[12];
    const float* mew1 = (const float*)d_in[13]; const float* meb1 = (const float*)d_in[14];
    const float* mnw0 = (const float*)d_in[15]; const float* mnb0 = (const float*)d_in[16];
    const float* cw0  = (const float*)d_in[17]; const float* cb0  = (const float*)d_in[18];
    const float* cw1  = (const float*)d_in[19]; const float* cb1  = (const float*)d_in[20];
    const float* cw2  = (const float*)d_in[21]; const float* cb2  = (const float*)d_in[22];

    const int N = in_sizes[0] / NIN;   // 20000
    const int E = in_sizes[2] / 2;     // 100000
    const int* srcj = eidx;            // edge_index[0] = j (source)
    const int* tgti = eidx + E;        // edge_index[1] = i (target)

    char* wsb = (char*)d_ws;
    unsigned short* nf0_bf = (unsigned short*)wsb;          // N*ND
    unsigned short* nf_bf  = nf0_bf + (size_t)N * ND;
    unsigned short* ef0_bf = nf_bf + (size_t)N * ND;
    unsigned short* ef_bf  = ef0_bf + (size_t)E * ED;
    unsigned short* msg    = ef_bf + (size_t)E * ED;        // E*ND bf16 messages
    unsigned short* w0F  = msg + (size_t)E * ND;            // frag-ordered [96][64][8]
    unsigned short* w1F  = w0F + 49152;                     // frag-ordered [16][64][8]
    unsigned short* wmF  = w1F + 8192;                      // frag-ordered [96][64][8]
    unsigned short* w0eT = wmF + 49152;                     // [64][KPAD]
    unsigned short* w1eT = w0eT + 64 * KPAD;                // [128][64]
    unsigned short* cw0T = w1eT + 8192;                     // [64][128]
    unsigned short* w0nT = cw0T + 8192;                     // [128][128]
    unsigned short* w1nT = w0nT + 16384;                    // [128][128]
    int* deg     = (int*)(w1nT + 16384);                    // N
    int* cursor  = deg + N;                                 // N (contiguous w/ deg)
    int* row_ptr = cursor + N;                              // N+1
    int* csr_eid = row_ptr + (N + 4);                       // E

    const int eblocks32 = (E + TM - 1) / TM;
    const int nblocks32 = (N + TM - 1) / TM;
    const int ntiles64 = (E + 63) / 64;

    wprep_k<<<(176128 + 255) / 256, 256, 0, stream>>>(mew0, mew1, mnw0, eew0, eew1, cw0,
                                                      new0, new1,
                                                      w0F, w1F, wmF, w0eT, w1eT, cw0T,
                                                      w0nT, w1nT);

    // CSR build (edge_index is constant across all 4 steps)
    zero_k<<<((2 * N) / 4 + 255) / 256, 256, 0, stream>>>((float*)deg, (2 * N) / 4);
    hist_k<<<(E + 255) / 256, 256, 0, stream>>>(tgti, deg, E);
    scan_k<<<1, 256, 0, stream>>>(deg, row_ptr, cursor, N, E);
    scatter_k<<<(E + 255) / 256, 256, 0, stream>>>(tgti, cursor, csr_eid, E);

    node_embed_k<<<nblocks32, 256, 0, stream>>>(x, w0nT, neb0, w1nT, neb1,
                                                nf0_bf, nf_bf, N);
    edge_embed_k<<<GSE, 256, 0, stream>>>(ea, w0eT, eeb0, w1eT, eeb1,
                                          ef0_bf, ef_bf, E, ntiles64);

    for (int s = 0; s < 4; s++) {
        edge_step_k<<<ntiles64, 256, 0, stream>>>(srcj, tgti, nf0_bf, nf_bf,
                                                  ef0_bf, ef_bf, msg,
                                                  w0F, meb0, w1F, meb1, wmF, mnb0,
                                                  E, (s < 3) ? 1 : 0);
        if (s < 3)
            agg_k<<<(N + 1) / 2, 256, 0, stream>>>(row_ptr, csr_eid, msg, nf_bf, N);
    }

    classify_k<<<eblocks32, 256, 0, stream>>>(ef_bf, cw0T, cb0, cw1, cb1, cw2, cb2,
                                              (float*)d_out, E);
}

// Round 10
// 860.311 us; speedup vs baseline: 1.0808x; 1.0808x over previous
//
#include <hip/hip_runtime.h>
#include <hip/hip_bf16.h>

#define ND 128
#define ED 128
#define NIN 128
#define EIN 291
#define KPAD 320   // EIN padded to multiple of 32 (w0eT row stride)
#define KP2 324    // aT LDS row stride (324 dwords/2 -> 648B: breaks 32-bank pow2 conflict)
#define HH 64
#define TM 32      // nodes per block in node-embed / edges per block in classify
#define TS 64      // edges per block in edge_step
#define SEGS 81    // KP2/4 float4-segments per ea row

typedef __attribute__((ext_vector_type(8))) short short8;
typedef __attribute__((ext_vector_type(4))) float float4_;

__device__ __forceinline__ unsigned short f2bf(float f)
{
    union { float f; unsigned u; } v; v.f = f;
    unsigned u = v.u;
    unsigned r = (u + 0x7FFFu + ((u >> 16) & 1u)) >> 16;  // RNE
    return (unsigned short)r;
}
__device__ __forceinline__ float bf2f(unsigned short s)
{
    union { unsigned u; float f; } v; v.u = ((unsigned)s) << 16;
    return v.f;
}

// Stage T N-tiles x KC k-chunks of B (layout [col][K], bf16) into LDS in MFMA
// FRAGMENT ORDER: fragment f=tt*KC+kc occupies 64 consecutive short8 slots.
template<int T, int KC, int K>
__device__ __forceinline__ void stage_frags(const unsigned short* __restrict__ src,
                                            unsigned short* __restrict__ wreg,
                                            int t, int k0)
{
    constexpr int TOT = T * KC * 64;
#pragma unroll
    for (int it = 0; it < TOT / 256; it++) {
        int idx = it * 256 + t;
        int f = idx >> 6, l = idx & 63;
        int col = (f / KC) * 16 + (l & 15);
        int k = (f % KC) * 32 + ((l >> 4) * 8);
        *(short8*)&wreg[idx * 8] = *(const short8*)&src[(size_t)col * K + k0 + k];
    }
}
#define FRAG(wreg, f, lane) (*(const short8*)&(wreg)[(((f) << 6) + (lane)) * 8])

// Zero a buffer (16B granules).
__global__ __launch_bounds__(256) void zero_k(float* __restrict__ p, int n4)
{
    int idx = blockIdx.x * 256 + threadIdx.x;
    if (idx < n4) ((float4*)p)[idx] = make_float4(0.f, 0.f, 0.f, 0.f);
}

// ---- CSR build (once per launch; edge_index is constant across the 4 steps) ----
__global__ __launch_bounds__(256) void hist_k(const int* __restrict__ tgti,
                                              int* __restrict__ deg, int E)
{
    int e = blockIdx.x * 256 + threadIdx.x;
    if (e < E) atomicAdd(&deg[tgti[e]], 1);
}

// Single-block exclusive scan over deg[0..N) -> row_ptr & cursor.
__global__ __launch_bounds__(256) void scan_k(const int* __restrict__ deg,
                                              int* __restrict__ row_ptr,
                                              int* __restrict__ cursor, int N, int E)
{
    __shared__ int part[256];
    const int t = threadIdx.x;
    const int chunk = (N + 255) / 256;
    const int base = t * chunk;
    int s = 0;
    for (int k = 0; k < chunk; k++) { int idx = base + k; if (idx < N) s += deg[idx]; }
    part[t] = s;
    __syncthreads();
    for (int off = 1; off < 256; off <<= 1) {
        int v = (t >= off) ? part[t - off] : 0;
        __syncthreads();
        part[t] += v;
        __syncthreads();
    }
    int run = (t == 0) ? 0 : part[t - 1];
    for (int k = 0; k < chunk; k++) {
        int idx = base + k;
        if (idx < N) { row_ptr[idx] = run; cursor[idx] = run; run += deg[idx]; }
    }
    if (t == 255) row_ptr[N] = E;
}

__global__ __launch_bounds__(256) void scatter_k(const int* __restrict__ tgti,
                                                 int* __restrict__ cursor,
                                                 int* __restrict__ csr_eid, int E)
{
    int e = blockIdx.x * 256 + threadIdx.x;
    if (e < E) {
        int p = atomicAdd(&cursor[tgti[e]], 1);
        csr_eid[p] = e;
    }
}

// Segment-sum of messages at target nodes (coalesced 256B reads, no atomics).
__global__ __launch_bounds__(256) void agg_k(const int* __restrict__ row_ptr,
                                             const int* __restrict__ csr_eid,
                                             const unsigned short* __restrict__ msg,
                                             unsigned short* __restrict__ nf_bf, int N)
{
    int n = blockIdx.x * 2 + (threadIdx.x >> 7);
    int c = threadIdx.x & 127;
    if (n >= N) return;
    int beg = row_ptr[n], end = row_ptr[n + 1];
    float acc = 0.f;
    for (int k = beg; k < end; k++) {
        int e = csr_eid[k];
        acc += bf2f(msg[(size_t)e * ND + c]);
    }
    nf_bf[(size_t)n * ND + c] = f2bf(acc);
}

// One-time weight prep: transpose + fp32->bf16 (+ zero-pad K for edge-embed L1).
__global__ __launch_bounds__(256) void wprep_k(
    const float* __restrict__ mew0, const float* __restrict__ mew1, const float* __restrict__ mnw0,
    const float* __restrict__ eew0, const float* __restrict__ eew1, const float* __restrict__ cw0,
    const float* __restrict__ new0, const float* __restrict__ new1,
    unsigned short* __restrict__ w0T, unsigned short* __restrict__ w1T,
    unsigned short* __restrict__ wmT, unsigned short* __restrict__ w0eT,
    unsigned short* __restrict__ w1eT, unsigned short* __restrict__ cw0T,
    unsigned short* __restrict__ w0nT, unsigned short* __restrict__ w1nT)
{
    int idx = blockIdx.x * 256 + threadIdx.x;
    if (idx < 49152) {
        int c = idx / 768, k = idx % 768;
        w0T[idx] = f2bf(mew0[k * 64 + c]);
    } else if (idx < 57344) {
        int j = idx - 49152; int c = j / 64, k = j % 64;
        w1T[j] = f2bf(mew1[k * 128 + c]);
    } else if (idx < 106496) {
        int j = idx - 57344; int c = j / 384, k = j % 384;
        wmT[j] = f2bf(mnw0[k * 128 + c]);
    } else if (idx < 126976) {
        int j = idx - 106496; int c = j / KPAD, k = j % KPAD;
        w0eT[j] = (k < EIN) ? f2bf(eew0[k * 64 + c]) : (unsigned short)0;
    } else if (idx < 135168) {
        int j = idx - 126976; int c = j / 64, k = j % 64;
        w1eT[j] = f2bf(eew1[k * 128 + c]);
    } else if (idx < 143360) {
        int j = idx - 135168; int c = j / 128, k = j % 128;
        cw0T[j] = f2bf(cw0[k * 64 + c]);
    } else if (idx < 159744) {
        int j = idx - 143360; int c = j / 128, k = j % 128;
        w0nT[j] = f2bf(new0[k * 128 + c]);
    } else if (idx < 176128) {
        int j = idx - 159744; int c = j / 128, k = j % 128;
        w1nT[j] = f2bf(new1[k * 128 + c]);
    }
}

// MFMA node embed: 32 nodes/block (unchanged).
__global__ __launch_bounds__(256) void node_embed_k(
    const float* __restrict__ x,
    const unsigned short* __restrict__ w0nT, const float* __restrict__ b0,
    const unsigned short* __restrict__ w1nT, const float* __restrict__ b1,
    unsigned short* __restrict__ nf0_bf, unsigned short* __restrict__ nf_bf, int N)
{
    const int t = threadIdx.x;
    const int n0 = blockIdx.x * TM;
    __shared__ unsigned short wreg[8192];
    __shared__ unsigned short xin[TM][130];
    __shared__ unsigned short h_bf[TM][130];

#pragma unroll
    for (int it = 0; it < 4; it++) {
        int idx = it * 256 + t;
        int r = idx >> 5, c4 = idx & 31;
        int node = n0 + r; if (node >= N) node = N - 1;
        float4 v = *(const float4*)(x + (size_t)node * NIN + c4 * 4);
        unsigned lo = (unsigned)f2bf(v.x) | ((unsigned)f2bf(v.y) << 16);
        unsigned hi = (unsigned)f2bf(v.z) | ((unsigned)f2bf(v.w) << 16);
        *(uint2*)&xin[r][c4 * 4] = make_uint2(lo, hi);
    }

    const int w = t >> 6, lane = t & 63, quad = lane >> 4, n16 = lane & 15;
    const int m = w & 1, nh = w >> 1;

    float4_ acc[4];
#pragma unroll
    for (int q = 0; q < 4; q++) acc[q] = (float4_){0.f, 0.f, 0.f, 0.f};
#pragma unroll
    for (int hf = 0; hf < 2; hf++) {
        stage_frags<8, 2, 128>(w0nT, wreg, t, hf * 64);
        __syncthreads();
#pragma unroll
        for (int kc = 0; kc < 2; kc++) {
            short8 a = *(const short8*)&xin[m * 16 + n16][hf * 64 + kc * 32 + quad * 8];
#pragma unroll
            for (int tt = 0; tt < 4; tt++) {
                short8 b = FRAG(wreg, (nh * 4 + tt) * 2 + kc, lane);
                acc[tt] = __builtin_amdgcn_mfma_f32_16x16x32_bf16(a, b, acc[tt], 0, 0, 0);
            }
        }
        __syncthreads();
    }
#pragma unroll
    for (int tt = 0; tt < 4; tt++) {
        int c = nh * 64 + tt * 16 + n16;
        float bias = b0[c];
#pragma unroll
        for (int r4 = 0; r4 < 4; r4++)
            h_bf[m * 16 + quad * 4 + r4][c] = f2bf(fmaxf(acc[tt][r4] + bias, 0.f));
    }
    __syncthreads();

    float4_ acc2[4];
#pragma unroll
    for (int q = 0; q < 4; q++) acc2[q] = (float4_){0.f, 0.f, 0.f, 0.f};
#pragma unroll
    for (int hf = 0; hf < 2; hf++) {
        stage_frags<8, 2, 128>(w1nT, wreg, t, hf * 64);
        __syncthreads();
#pragma unroll
        for (int kc = 0; kc < 2; kc++) {
            short8 a = *(const short8*)&h_bf[m * 16 + n16][hf * 64 + kc * 32 + quad * 8];
#pragma unroll
            for (int tt = 0; tt < 4; tt++) {
                short8 b = FRAG(wreg, (nh * 4 + tt) * 2 + kc, lane);
                acc2[tt] = __builtin_amdgcn_mfma_f32_16x16x32_bf16(a, b, acc2[tt], 0, 0, 0);
            }
        }
        __syncthreads();
    }
#pragma unroll
    for (int tt = 0; tt < 4; tt++) {
        int c = nh * 64 + tt * 16 + n16;
        float bias = b1[c];
#pragma unroll
        for (int r4 = 0; r4 < 4; r4++) {
            int row = m * 16 + quad * 4 + r4;
            int node = n0 + row;
            if (node < N) {
                unsigned short v = f2bf(acc2[tt][r4] + bias);
                nf0_bf[(size_t)node * ND + c] = v;
                nf_bf[(size_t)node * ND + c] = v;
            }
        }
    }
}

// MFMA edge embed v3: 64 edges/block, 1 tile/block (1563 blocks).
// A-panel now staged COALESCED into LDS (fp32 read along rows, bf16 store),
// replacing the old per-lane 32B stride-1164B reads (~50% line efficiency,
// latency-serialized). aT stride KP2=324 (648B) avoids pow2 bank conflicts.
// Peak LDS = aT 41.5KB + w0reg 20KB + hsl 8.25KB = ~70KB -> 2 blocks/CU.
__global__ __launch_bounds__(256, 2) void edge_embed_k(
    const float* __restrict__ ea,
    const unsigned short* __restrict__ w0eT, const float* __restrict__ b0,
    const unsigned short* __restrict__ w1eT, const float* __restrict__ b1,
    unsigned short* __restrict__ ef0_bf, unsigned short* __restrict__ ef_bf,
    int E)
{
    const int t = threadIdx.x;
    const int e0 = blockIdx.x * 64;
    __shared__ unsigned short aT[64][KP2];     // 41.5 KB bf16 A-panel
    __shared__ unsigned short w0reg[10240];    // 20 KB: one K-half (T=4,KC=5); reused for w1
    __shared__ unsigned short hsl[4][16 * 66]; // 8.25 KB

    const int w = t >> 6, lane = t & 63, quad = lane >> 4, n16 = lane & 15;

    // ---- coalesced A staging: 64 rows x 81 float4-segs ----
    for (int it = 0; it < (64 * SEGS + 255) / 256; it++) {
        int idx = it * 256 + t;
        if (idx < 64 * SEGS) {
            int r = idx / SEGS, seg = idx % SEGS;
            int e = e0 + r; if (e >= E) e = E - 1;
            const float* src = ea + (size_t)e * EIN + seg * 4;
            unsigned short v[4];
            if (seg * 4 + 4 <= EIN) {
                float4 f = *(const float4*)src;
                v[0] = f2bf(f.x); v[1] = f2bf(f.y); v[2] = f2bf(f.z); v[3] = f2bf(f.w);
            } else {
#pragma unroll
                for (int j = 0; j < 4; j++)
                    v[j] = (seg * 4 + j < EIN) ? f2bf(src[j]) : (unsigned short)0;
            }
            *(uint2*)&aT[r][seg * 4] = make_uint2(
                (unsigned)v[0] | ((unsigned)v[1] << 16),
                (unsigned)v[2] | ((unsigned)v[3] << 16));
        }
    }

    const int arow = w * 16 + n16;
    float4_ accL[4];
#pragma unroll
    for (int q = 0; q < 4; q++) accL[q] = (float4_){0.f, 0.f, 0.f, 0.f};

#pragma unroll
    for (int hf = 0; hf < 2; hf++) {
        if (hf) __syncthreads();               // protect w0reg overwrite
        stage_frags<4, 5, KPAD>(w0eT, w0reg, t, hf * 160);
        __syncthreads();                       // covers aT (hf=0) + w0reg
#pragma unroll
        for (int kc = 0; kc < 5; kc++) {
            short8 a = *(const short8*)&aT[arow][hf * 160 + kc * 32 + quad * 8];
#pragma unroll
            for (int tt = 0; tt < 4; tt++) {
                short8 b = FRAG(w0reg, tt * 5 + kc, lane);
                accL[tt] = __builtin_amdgcn_mfma_f32_16x16x32_bf16(a, b, accL[tt], 0, 0, 0);
            }
        }
    }

    // L0 epilogue -> per-wave hsl (no barrier: own-wave band)
#pragma unroll
    for (int tt = 0; tt < 4; tt++) {
        int c = tt * 16 + n16;
        float bias = b0[c];
#pragma unroll
        for (int r4 = 0; r4 < 4; r4++)
            hsl[w][(quad * 4 + r4) * 66 + c] = f2bf(fmaxf(accL[tt][r4] + bias, 0.f));
    }

    // ---- L1: stage w1 into w0reg region ----
    __syncthreads();                           // all waves done reading w0
    stage_frags<8, 2, 64>(w1eT, w0reg, t, 0);  // 16 KB
    __syncthreads();
    {
        float4_ acc2[8];
#pragma unroll
        for (int q = 0; q < 8; q++) acc2[q] = (float4_){0.f, 0.f, 0.f, 0.f};
#pragma unroll
        for (int kc = 0; kc < 2; kc++) {
            short8 a2 = *(const short8*)&hsl[w][n16 * 66 + kc * 32 + quad * 8];
#pragma unroll
            for (int tt = 0; tt < 8; tt++)
                acc2[tt] = __builtin_amdgcn_mfma_f32_16x16x32_bf16(
                    a2, FRAG(w0reg, tt * 2 + kc, lane), acc2[tt], 0, 0, 0);
        }
#pragma unroll
        for (int tt = 0; tt < 8; tt++) {
            int c = tt * 16 + n16;
            float bias = b1[c];
#pragma unroll
            for (int r4 = 0; r4 < 4; r4++) {
                int e = e0 + w * 16 + quad * 4 + r4;
                if (e < E) {
                    unsigned short v = f2bf(acc2[tt][r4] + bias);  // no ReLU
                    ef0_bf[(size_t)e * ED + c] = v;
                    ef_bf[(size_t)e * ED + c] = v;
                }
            }
        }
    }
}

// MFMA MPN step (R4 structure — best measured at 96us): 64 edges/block, 4
// waves; JIT A-fragment loads per phase; 32KB weight chunks (7 barrier
// phases); h/efn unioned per-wave band. LDS 49.7KB -> 3 blocks/CU.
__global__ __launch_bounds__(256, 3) void edge_step_k(
    const int* __restrict__ srcj, const int* __restrict__ tgti,
    const unsigned short* __restrict__ nf0_bf, const unsigned short* __restrict__ nf_bf,
    const unsigned short* __restrict__ ef0_bf, unsigned short* __restrict__ ef_bf,
    unsigned short* __restrict__ msg,
    const unsigned short* __restrict__ w0T, const float* __restrict__ meb0,
    const unsigned short* __restrict__ w1T, const float* __restrict__ meb1,
    const unsigned short* __restrict__ wmT, const float* __restrict__ mnb0,
    int E, int wmsg)
{
    const int t = threadIdx.x;
    const int e0 = blockIdx.x * TS;
    __shared__ unsigned short wreg[16384];     // 32KB weight staging
    __shared__ unsigned short hef[4][2080];    // per-wave band: h(66) then efn(130)

    const int w = t >> 6, lane = t & 63, quad = lane >> 4, n16 = lane & 15;
    int ec = e0 + w * 16 + n16; if (ec >= E) ec = E - 1;
    const int ti = tgti[ec], sj = srcj[ec];

    const unsigned short* pA[6] = {
        nf0_bf + (size_t)ti * ND + quad * 8,
        nf_bf  + (size_t)ti * ND + quad * 8,
        nf0_bf + (size_t)sj * ND + quad * 8,
        nf_bf  + (size_t)sj * ND + quad * 8,
        ef0_bf + (size_t)ec * ED + quad * 8,
        ef_bf  + (size_t)ec * ED + quad * 8 };

    // ---- edge MLP layer 0: [64x768]x[768->64], K in 3 chunks of 256 ----
    float4_ accL[4];
#pragma unroll
    for (int q = 0; q < 4; q++) accL[q] = (float4_){0.f, 0.f, 0.f, 0.f};
#pragma unroll
    for (int hf = 0; hf < 3; hf++) {
        short8 a8[8];
#pragma unroll
        for (int q2 = 0; q2 < 8; q2++)
            a8[q2] = *(const short8*)(pA[hf * 2 + (q2 >> 2)] + (q2 & 3) * 32);
        stage_frags<4, 8, 768>(w0T, wreg, t, hf * 256);
        __syncthreads();
#pragma unroll
        for (int kc = 0; kc < 8; kc++) {
#pragma unroll
            for (int tt = 0; tt < 4; tt++) {
                short8 b = FRAG(wreg, tt * 8 + kc, lane);
                accL[tt] = __builtin_amdgcn_mfma_f32_16x16x32_bf16(a8[kc], b, accL[tt], 0, 0, 0);
            }
        }
        __syncthreads();
    }

    // L0 epilogue -> h in own-wave band (stride 66), no barrier needed
#pragma unroll
    for (int tt = 0; tt < 4; tt++) {
        int c = tt * 16 + n16;
        float bias = meb0[c];
#pragma unroll
        for (int r4 = 0; r4 < 4; r4++)
            hef[w][(quad * 4 + r4) * 66 + c] = f2bf(fmaxf(accL[tt][r4] + bias, 0.f));
    }

    // ---- edge MLP layer 1: [64x64]x[64->128] ----
    stage_frags<8, 2, 64>(w1T, wreg, t, 0);    // 16KB into wreg
    __syncthreads();
    {
        float4_ acc[8];
#pragma unroll
        for (int q = 0; q < 8; q++) acc[q] = (float4_){0.f, 0.f, 0.f, 0.f};
#pragma unroll
        for (int kc = 0; kc < 2; kc++) {
            short8 a = *(const short8*)&hef[w][n16 * 66 + kc * 32 + quad * 8];
#pragma unroll
            for (int tt = 0; tt < 8; tt++) {
                short8 b = FRAG(wreg, tt * 2 + kc, lane);
                acc[tt] = __builtin_amdgcn_mfma_f32_16x16x32_bf16(a, b, acc[tt], 0, 0, 0);
            }
        }
        // epilogue: efn into own-wave band (stride 130) + global ef store
#pragma unroll
        for (int tt = 0; tt < 8; tt++) {
            int c = tt * 16 + n16;
            float bias = meb1[c];
#pragma unroll
            for (int r4 = 0; r4 < 4; r4++) {
                int row = quad * 4 + r4;
                unsigned short v = f2bf(fmaxf(acc[tt][r4] + bias, 0.f));
                hef[w][row * 130 + c] = v;
                int e = e0 + w * 16 + row;
                if (e < E) ef_bf[(size_t)e * ED + c] = v;
            }
        }
    }
    __syncthreads();

    // ---- node-message MLP: [64x384]x[384->128], K in 3 chunks of 128 ----
    // (skipped on the last step: final nf is never consumed)
    if (wmsg) {
        float4_ accM[8];
#pragma unroll
        for (int q = 0; q < 8; q++) accM[q] = (float4_){0.f, 0.f, 0.f, 0.f};
#pragma unroll
        for (int j = 0; j < 3; j++) {
            short8 a4[4];
            if (j < 2) {
#pragma unroll
                for (int q2 = 0; q2 < 4; q2++)
                    a4[q2] = *(const short8*)(pA[j] + q2 * 32);
            } else {
#pragma unroll
                for (int q2 = 0; q2 < 4; q2++)
                    a4[q2] = *(const short8*)&hef[w][n16 * 130 + q2 * 32 + quad * 8];
            }
            stage_frags<8, 4, 384>(wmT, wreg, t, j * 128);
            __syncthreads();
#pragma unroll
            for (int kc = 0; kc < 4; kc++) {
#pragma unroll
                for (int tt = 0; tt < 8; tt++) {
                    short8 b = FRAG(wreg, tt * 4 + kc, lane);
                    accM[tt] = __builtin_amdgcn_mfma_f32_16x16x32_bf16(a4[kc], b, accM[tt], 0, 0, 0);
                }
            }
            __syncthreads();
        }
#pragma unroll
        for (int tt = 0; tt < 8; tt++) {
            int c = tt * 16 + n16;
            float bias = mnb0[c];
#pragma unroll
            for (int r4 = 0; r4 < 4; r4++) {
                int row = w * 16 + quad * 4 + r4;
                int e = e0 + row;
                if (e < E)
                    msg[(size_t)e * ND + c] = f2bf(fmaxf(accM[tt][r4] + bias, 0.f));
            }
        }
    }
}

// classify (unchanged).
__global__ __launch_bounds__(256) void classify_k(
    const unsigned short* __restrict__ ef_bf,
    const unsigned short* __restrict__ cw0T, const float* __restrict__ cb0,
    const float* __restrict__ cw1, const float* __restrict__ cb1,
    const float* __restrict__ cw2, const float* __restrict__ cb2,
    float* __restrict__ out, int E)
{
    const int t = threadIdx.x;
    const int e0 = blockIdx.x * TM;
    __shared__ unsigned short h0_bf[TM][66];
    __shared__ float h1[TM][33];

    const int w = t >> 6, lane = t & 63, quad = lane >> 4, n16 = lane & 15;
    const int m = w & 1;
    const int erow = m * 16 + n16;
    int ec = e0 + erow; if (ec >= E) ec = E - 1;
    const unsigned short* pa = ef_bf + (size_t)ec * ED + quad * 8;

    {
        const int cb = (w >> 1) * 32;
        float4_ acc0 = {0.f, 0.f, 0.f, 0.f}, acc1 = acc0;
        const unsigned short* b0p = cw0T + (size_t)(cb + n16) * 128 + quad * 8;
        const unsigned short* b1p = b0p + (size_t)16 * 128;
#pragma unroll
        for (int kc = 0; kc < 4; kc++) {
            short8 a  = *(const short8*)(pa + kc * 32);
            short8 bb0 = *(const short8*)(b0p + kc * 32);
            short8 bb1 = *(const short8*)(b1p + kc * 32);
            acc0 = __builtin_amdgcn_mfma_f32_16x16x32_bf16(a, bb0, acc0, 0, 0, 0);
            acc1 = __builtin_amdgcn_mfma_f32_16x16x32_bf16(a, bb1, acc1, 0, 0, 0);
        }
#pragma unroll
        for (int t2 = 0; t2 < 2; t2++) {
            int c = cb + t2 * 16 + n16;
            float bias = cb0[c];
            float4_ ac = t2 ? acc1 : acc0;
#pragma unroll
            for (int r4 = 0; r4 < 4; r4++)
                h0_bf[m * 16 + quad * 4 + r4][c] = f2bf(fmaxf(ac[r4] + bias, 0.f));
        }
    }
    __syncthreads();

    {
        int c = t & 31;
        int rbase = (t >> 5) * 4;
#pragma unroll
        for (int q = 0; q < 4; q++) {
            int r = rbase + q;
            float acc = cb1[c];
#pragma unroll 8
            for (int k = 0; k < 64; k++) acc += bf2f(h0_bf[r][k]) * cw1[k * 32 + c];
            h1[r][c] = fmaxf(acc, 0.f);
        }
    }
    __syncthreads();

    if (t < TM) {
        int e = e0 + t;
        if (e < E) {
            float a = cb2[0];
#pragma unroll
            for (int k = 0; k < 32; k++) a += h1[t][k] * cw2[k];
            out[e] = a;
        }
    }
}

extern "C" void kernel_launch(void* const* d_in, const int* in_sizes, int n_in,
                              void* d_out, int out_size, void* d_ws, size_t ws_size,
                              hipStream_t stream)
{
    const float* x    = (const float*)d_in[0];
    const float* ea   = (const float*)d_in[1];
    const int*   eidx = (const int*)d_in[2];
    const float* new0 = (const float*)d_in[3];  const float* neb0 = (const float*)d_in[4];
    const float* new1 = (const float*)d_in[5];  const float* neb1 = (const float*)d_in[6];
    const float* eew0 = (const float*)d_in[7];  const float* eeb0 = (const float*)d_in[8];
    const float* eew1 = (const float*)d_in[9];  const float* eeb1 = (const float*)d_in[10];
    const float* mew0 = (const float*)d_in[11]; const float* meb0 = (const float*)d_in[12];
    const float* mew1 = (const float*)d_in[13]; const float* meb1 = (const float*)d_in[14];
    const float* mnw0 = (const float*)d_in[15]; const float* mnb0 = (const float*)d_in[16];
    const float* cw0  = (const float*)d_in[17]; const float* cb0  = (const float*)d_in[18];
    const float* cw1  = (const float*)d_in[19]; const float* cb1  = (const float*)d_in[20];
    const float* cw2  = (const float*)d_in[21]; const float* cb2  = (const float*)d_in[22];

    const int N = in_sizes[0] / NIN;   // 20000
    const int E = in_sizes[2] / 2;     // 100000
    const int* srcj = eidx;            // edge_index[0] = j (source)
    const int* tgti = eidx + E;        // edge_index[1] = i (target)

    char* wsb = (char*)d_ws;
    unsigned short* nf0_bf = (unsigned short*)wsb;          // N*ND
    unsigned short* nf_bf  = nf0_bf + (size_t)N * ND;
    unsigned short* ef0_bf = nf_bf + (size_t)N * ND;
    unsigned short* ef_bf  = ef0_bf + (size_t)E * ED;
    unsigned short* msg    = ef_bf + (size_t)E * ED;        // E*ND bf16 messages
    unsigned short* w0T  = msg + (size_t)E * ND;            // [64][768]
    unsigned short* w1T  = w0T + 49152;                     // [128][64]
    unsigned short* wmT  = w1T + 8192;                      // [128][384]
    unsigned short* w0eT = wmT + 49152;                     // [64][KPAD]
    unsigned short* w1eT = w0eT + 64 * KPAD;                // [128][64]
    unsigned short* cw0T = w1eT + 8192;                     // [64][128]
    unsigned short* w0nT = cw0T + 8192;                     // [128][128]
    unsigned short* w1nT = w0nT + 16384;                    // [128][128]
    int* deg     = (int*)(w1nT + 16384);                    // N
    int* cursor  = deg + N;                                 // N (contiguous w/ deg)
    int* row_ptr = cursor + N;                              // N+1
    int* csr_eid = row_ptr + (N + 4);                       // E

    const int eblocks32 = (E + TM - 1) / TM;
    const int nblocks32 = (N + TM - 1) / TM;
    const int ntiles64 = (E + 63) / 64;

    wprep_k<<<(176128 + 255) / 256, 256, 0, stream>>>(mew0, mew1, mnw0, eew0, eew1, cw0,
                                                      new0, new1,
                                                      w0T, w1T, wmT, w0eT, w1eT, cw0T,
                                                      w0nT, w1nT);

    // CSR build (edge_index is constant across all 4 steps)
    zero_k<<<((2 * N) / 4 + 255) / 256, 256, 0, stream>>>((float*)deg, (2 * N) / 4);
    hist_k<<<(E + 255) / 256, 256, 0, stream>>>(tgti, deg, E);
    scan_k<<<1, 256, 0, stream>>>(deg, row_ptr, cursor, N, E);
    scatter_k<<<(E + 255) / 256, 256, 0, stream>>>(tgti, cursor, csr_eid, E);

    node_embed_k<<<nblocks32, 256, 0, stream>>>(x, w0nT, neb0, w1nT, neb1,
                                                nf0_bf, nf_bf, N);
    edge_embed_k<<<ntiles64, 256, 0, stream>>>(ea, w0eT, eeb0, w1eT, eeb1,
                                               ef0_bf, ef_bf, E);

    for (int s = 0; s < 4; s++) {
        edge_step_k<<<ntiles64, 256, 0, stream>>>(srcj, tgti, nf0_bf, nf_bf,
                                                  ef0_bf, ef_bf, msg,
                                                  w0T, meb0, w1T, meb1, wmT, mnb0,
                                                  E, (s < 3) ? 1 : 0);
        if (s < 3)
            agg_k<<<(N + 1) / 2, 256, 0, stream>>>(row_ptr, csr_eid, msg, nf_bf, N);
    }

    classify_k<<<eblocks32, 256, 0, stream>>>(ef_bf, cw0T, cb0, cw1, cb1, cw2, cb2,
                                              (float*)d_out, E);
}

// Round 11
// 729.533 us; speedup vs baseline: 1.2745x; 1.1793x over previous
//
#include <hip/hip_runtime.h>
#include <hip/hip_bf16.h>

#define ND 128
#define ED 128
#define NIN 128
#define EIN 291
#define KPAD 320   // EIN padded to multiple of 32 (w0eT row stride)
#define HH 64
#define TM 32      // nodes per block in node-embed / edges per block in classify
#define TS 64      // edges per block in edge_step
#define GSE 768    // grid blocks for edge_embed (3 per CU)
#define MAXGE 3    // max 64-edge tiles per edge_embed block

typedef __attribute__((ext_vector_type(8))) short short8;
typedef __attribute__((ext_vector_type(4))) float float4_;

__device__ __forceinline__ unsigned short f2bf(float f)
{
    union { float f; unsigned u; } v; v.f = f;
    unsigned u = v.u;
    unsigned r = (u + 0x7FFFu + ((u >> 16) & 1u)) >> 16;  // RNE
    return (unsigned short)r;
}
__device__ __forceinline__ float bf2f(unsigned short s)
{
    union { unsigned u; float f; } v; v.u = ((unsigned)s) << 16;
    return v.f;
}

// Stage T N-tiles x KC k-chunks of B (layout [col][K], bf16) into LDS in MFMA
// FRAGMENT ORDER: fragment f=tt*KC+kc occupies 64 consecutive short8 slots.
template<int T, int KC, int K>
__device__ __forceinline__ void stage_frags(const unsigned short* __restrict__ src,
                                            unsigned short* __restrict__ wreg,
                                            int t, int k0)
{
    constexpr int TOT = T * KC * 64;
#pragma unroll
    for (int it = 0; it < TOT / 256; it++) {
        int idx = it * 256 + t;
        int f = idx >> 6, l = idx & 63;
        int col = (f / KC) * 16 + (l & 15);
        int k = (f % KC) * 32 + ((l >> 4) * 8);
        *(short8*)&wreg[idx * 8] = *(const short8*)&src[(size_t)col * K + k0 + k];
    }
}
#define FRAG(wreg, f, lane) (*(const short8*)&(wreg)[(((f) << 6) + (lane)) * 8])

// Zero a buffer (16B granules).
__global__ __launch_bounds__(256) void zero_k(float* __restrict__ p, int n4)
{
    int idx = blockIdx.x * 256 + threadIdx.x;
    if (idx < n4) ((float4*)p)[idx] = make_float4(0.f, 0.f, 0.f, 0.f);
}

// ---- CSR build (once per launch; edge_index is constant across the 4 steps) ----
__global__ __launch_bounds__(256) void hist_k(const int* __restrict__ tgti,
                                              int* __restrict__ deg, int E)
{
    int e = blockIdx.x * 256 + threadIdx.x;
    if (e < E) atomicAdd(&deg[tgti[e]], 1);
}

// Single-block exclusive scan over deg[0..N) -> row_ptr & cursor.
__global__ __launch_bounds__(256) void scan_k(const int* __restrict__ deg,
                                              int* __restrict__ row_ptr,
                                              int* __restrict__ cursor, int N, int E)
{
    __shared__ int part[256];
    const int t = threadIdx.x;
    const int chunk = (N + 255) / 256;
    const int base = t * chunk;
    int s = 0;
    for (int k = 0; k < chunk; k++) { int idx = base + k; if (idx < N) s += deg[idx]; }
    part[t] = s;
    __syncthreads();
    for (int off = 1; off < 256; off <<= 1) {
        int v = (t >= off) ? part[t - off] : 0;
        __syncthreads();
        part[t] += v;
        __syncthreads();
    }
    int run = (t == 0) ? 0 : part[t - 1];
    for (int k = 0; k < chunk; k++) {
        int idx = base + k;
        if (idx < N) { row_ptr[idx] = run; cursor[idx] = run; run += deg[idx]; }
    }
    if (t == 255) row_ptr[N] = E;
}

__global__ __launch_bounds__(256) void scatter_k(const int* __restrict__ tgti,
                                                 int* __restrict__ cursor,
                                                 int* __restrict__ csr_eid, int E)
{
    int e = blockIdx.x * 256 + threadIdx.x;
    if (e < E) {
        int p = atomicAdd(&cursor[tgti[e]], 1);
        csr_eid[p] = e;
    }
}

// Positional src/tgt arrays in CSR (target-sorted) order: consecutive
// positions share targets -> L1-local ti-gathers in edge_step, and agg
// becomes a contiguous segment reduce.
__global__ __launch_bounds__(256) void permidx_k(const int* __restrict__ csr_eid,
                                                 const int* __restrict__ srcj,
                                                 const int* __restrict__ tgti,
                                                 int* __restrict__ srcp,
                                                 int* __restrict__ tgtp, int E)
{
    int p = blockIdx.x * 256 + threadIdx.x;
    if (p < E) {
        int e = csr_eid[p];
        srcp[p] = srcj[e];
        tgtp[p] = tgti[e];
    }
}

// Segment-sum of messages: msg is stored in CSR position order, so node n's
// messages are CONTIGUOUS rows [row_ptr[n], row_ptr[n+1]) — pure stream.
__global__ __launch_bounds__(256) void agg_k(const int* __restrict__ row_ptr,
                                             const unsigned short* __restrict__ msg,
                                             unsigned short* __restrict__ nf_bf, int N)
{
    int n = blockIdx.x * 2 + (threadIdx.x >> 7);
    int c = threadIdx.x & 127;
    if (n >= N) return;
    int beg = row_ptr[n], end = row_ptr[n + 1];
    float acc = 0.f;
    for (int p = beg; p < end; p++)
        acc += bf2f(msg[(size_t)p * ND + c]);
    nf_bf[(size_t)n * ND + c] = f2bf(acc);
}

// One-time weight prep: transpose + fp32->bf16 (+ zero-pad K for edge-embed L1).
__global__ __launch_bounds__(256) void wprep_k(
    const float* __restrict__ mew0, const float* __restrict__ mew1, const float* __restrict__ mnw0,
    const float* __restrict__ eew0, const float* __restrict__ eew1, const float* __restrict__ cw0,
    const float* __restrict__ new0, const float* __restrict__ new1,
    unsigned short* __restrict__ w0T, unsigned short* __restrict__ w1T,
    unsigned short* __restrict__ wmT, unsigned short* __restrict__ w0eT,
    unsigned short* __restrict__ w1eT, unsigned short* __restrict__ cw0T,
    unsigned short* __restrict__ w0nT, unsigned short* __restrict__ w1nT)
{
    int idx = blockIdx.x * 256 + threadIdx.x;
    if (idx < 49152) {
        int c = idx / 768, k = idx % 768;
        w0T[idx] = f2bf(mew0[k * 64 + c]);
    } else if (idx < 57344) {
        int j = idx - 49152; int c = j / 64, k = j % 64;
        w1T[j] = f2bf(mew1[k * 128 + c]);
    } else if (idx < 106496) {
        int j = idx - 57344; int c = j / 384, k = j % 384;
        wmT[j] = f2bf(mnw0[k * 128 + c]);
    } else if (idx < 126976) {
        int j = idx - 106496; int c = j / KPAD, k = j % KPAD;
        w0eT[j] = (k < EIN) ? f2bf(eew0[k * 64 + c]) : (unsigned short)0;
    } else if (idx < 135168) {
        int j = idx - 126976; int c = j / 64, k = j % 64;
        w1eT[j] = f2bf(eew1[k * 128 + c]);
    } else if (idx < 143360) {
        int j = idx - 135168; int c = j / 128, k = j % 128;
        cw0T[j] = f2bf(cw0[k * 64 + c]);
    } else if (idx < 159744) {
        int j = idx - 143360; int c = j / 128, k = j % 128;
        w0nT[j] = f2bf(new0[k * 128 + c]);
    } else if (idx < 176128) {
        int j = idx - 159744; int c = j / 128, k = j % 128;
        w1nT[j] = f2bf(new1[k * 128 + c]);
    }
}

// MFMA node embed: 32 nodes/block (unchanged).
__global__ __launch_bounds__(256) void node_embed_k(
    const float* __restrict__ x,
    const unsigned short* __restrict__ w0nT, const float* __restrict__ b0,
    const unsigned short* __restrict__ w1nT, const float* __restrict__ b1,
    unsigned short* __restrict__ nf0_bf, unsigned short* __restrict__ nf_bf, int N)
{
    const int t = threadIdx.x;
    const int n0 = blockIdx.x * TM;
    __shared__ unsigned short wreg[8192];
    __shared__ unsigned short xin[TM][130];
    __shared__ unsigned short h_bf[TM][130];

#pragma unroll
    for (int it = 0; it < 4; it++) {
        int idx = it * 256 + t;
        int r = idx >> 5, c4 = idx & 31;
        int node = n0 + r; if (node >= N) node = N - 1;
        float4 v = *(const float4*)(x + (size_t)node * NIN + c4 * 4);
        unsigned lo = (unsigned)f2bf(v.x) | ((unsigned)f2bf(v.y) << 16);
        unsigned hi = (unsigned)f2bf(v.z) | ((unsigned)f2bf(v.w) << 16);
        *(uint2*)&xin[r][c4 * 4] = make_uint2(lo, hi);
    }

    const int w = t >> 6, lane = t & 63, quad = lane >> 4, n16 = lane & 15;
    const int m = w & 1, nh = w >> 1;

    float4_ acc[4];
#pragma unroll
    for (int q = 0; q < 4; q++) acc[q] = (float4_){0.f, 0.f, 0.f, 0.f};
#pragma unroll
    for (int hf = 0; hf < 2; hf++) {
        stage_frags<8, 2, 128>(w0nT, wreg, t, hf * 64);
        __syncthreads();
#pragma unroll
        for (int kc = 0; kc < 2; kc++) {
            short8 a = *(const short8*)&xin[m * 16 + n16][hf * 64 + kc * 32 + quad * 8];
#pragma unroll
            for (int tt = 0; tt < 4; tt++) {
                short8 b = FRAG(wreg, (nh * 4 + tt) * 2 + kc, lane);
                acc[tt] = __builtin_amdgcn_mfma_f32_16x16x32_bf16(a, b, acc[tt], 0, 0, 0);
            }
        }
        __syncthreads();
    }
#pragma unroll
    for (int tt = 0; tt < 4; tt++) {
        int c = nh * 64 + tt * 16 + n16;
        float bias = b0[c];
#pragma unroll
        for (int r4 = 0; r4 < 4; r4++)
            h_bf[m * 16 + quad * 4 + r4][c] = f2bf(fmaxf(acc[tt][r4] + bias, 0.f));
    }
    __syncthreads();

    float4_ acc2[4];
#pragma unroll
    for (int q = 0; q < 4; q++) acc2[q] = (float4_){0.f, 0.f, 0.f, 0.f};
#pragma unroll
    for (int hf = 0; hf < 2; hf++) {
        stage_frags<8, 2, 128>(w1nT, wreg, t, hf * 64);
        __syncthreads();
#pragma unroll
        for (int kc = 0; kc < 2; kc++) {
            short8 a = *(const short8*)&h_bf[m * 16 + n16][hf * 64 + kc * 32 + quad * 8];
#pragma unroll
            for (int tt = 0; tt < 4; tt++) {
                short8 b = FRAG(wreg, (nh * 4 + tt) * 2 + kc, lane);
                acc2[tt] = __builtin_amdgcn_mfma_f32_16x16x32_bf16(a, b, acc2[tt], 0, 0, 0);
            }
        }
        __syncthreads();
    }
#pragma unroll
    for (int tt = 0; tt < 4; tt++) {
        int c = nh * 64 + tt * 16 + n16;
        float bias = b1[c];
#pragma unroll
        for (int r4 = 0; r4 < 4; r4++) {
            int row = m * 16 + quad * 4 + r4;
            int node = n0 + row;
            if (node < N) {
                unsigned short v = f2bf(acc2[tt][r4] + bias);
                nf0_bf[(size_t)node * ND + c] = v;
                nf_bf[(size_t)node * ND + c] = v;
            }
        }
    }
}

// MFMA edge embed (R4 structure — all 768 blocks co-resident, weights staged
// once per block for 3 tiles) + CSR-permuted source rows: tile position p
// reads ea[csr_eid[p]], writes ef at position p.
__global__ __launch_bounds__(256, 3) void edge_embed_k(
    const float* __restrict__ ea, const int* __restrict__ csr_eid,
    const unsigned short* __restrict__ w0eT, const float* __restrict__ b0,
    const unsigned short* __restrict__ w1eT, const float* __restrict__ b1,
    unsigned short* __restrict__ ef0_bf, unsigned short* __restrict__ ef_bf,
    int E, int ntiles)
{
    const int t = threadIdx.x;
    __shared__ unsigned short w0reg[10240];   // 20KB: one K-half (T=4, KC=5)
    __shared__ unsigned short w1reg[8192];    // 16KB: w1e full (T=8, KC=2)
    __shared__ unsigned short hsl[4][16 * 66];

    const int w = t >> 6, lane = t & 63, quad = lane >> 4, n16 = lane & 15;

    stage_frags<8, 2, 64>(w1eT, w1reg, t, 0);   // covered by first barrier below

    int ng = 0;
    int tile[MAXGE];
#pragma unroll
    for (int g = 0; g < MAXGE; g++) {
        int tl = blockIdx.x + g * GSE;
        if (tl < ntiles) { tile[g] = tl; ng = g + 1; }
        else tile[g] = 0;
    }

    float4_ accL[MAXGE][4];
#pragma unroll
    for (int g = 0; g < MAXGE; g++)
#pragma unroll
        for (int q = 0; q < 4; q++) accL[g][q] = (float4_){0.f, 0.f, 0.f, 0.f};

#pragma unroll
    for (int hf = 0; hf < 2; hf++) {
        __syncthreads();
        stage_frags<4, 5, KPAD>(w0eT, w0reg, t, hf * 160);
        __syncthreads();
#pragma unroll
        for (int g = 0; g < MAXGE; g++) {
            if (g < ng) {
                int p = tile[g] * 64 + w * 16 + n16; if (p >= E) p = E - 1;
                const float* src = ea + (size_t)csr_eid[p] * EIN;
#pragma unroll
                for (int kc = 0; kc < 5; kc++) {
                    int k = hf * 160 + kc * 32 + quad * 8;
                    union { short8 s; uint4 u; } av;
                    if (k + 8 <= EIN) {
                        float4 v0 = *(const float4*)(src + k);
                        float4 v1 = *(const float4*)(src + k + 4);
                        av.u.x = (unsigned)f2bf(v0.x) | ((unsigned)f2bf(v0.y) << 16);
                        av.u.y = (unsigned)f2bf(v0.z) | ((unsigned)f2bf(v0.w) << 16);
                        av.u.z = (unsigned)f2bf(v1.x) | ((unsigned)f2bf(v1.y) << 16);
                        av.u.w = (unsigned)f2bf(v1.z) | ((unsigned)f2bf(v1.w) << 16);
                    } else {
                        unsigned short vv[8];
#pragma unroll
                        for (int j = 0; j < 8; j++)
                            vv[j] = (k + j < EIN) ? f2bf(src[k + j]) : (unsigned short)0;
                        av.u.x = (unsigned)vv[0] | ((unsigned)vv[1] << 16);
                        av.u.y = (unsigned)vv[2] | ((unsigned)vv[3] << 16);
                        av.u.z = (unsigned)vv[4] | ((unsigned)vv[5] << 16);
                        av.u.w = (unsigned)vv[6] | ((unsigned)vv[7] << 16);
                    }
#pragma unroll
                    for (int tt = 0; tt < 4; tt++) {
                        short8 b = FRAG(w0reg, tt * 5 + kc, lane);
                        accL[g][tt] = __builtin_amdgcn_mfma_f32_16x16x32_bf16(av.s, b, accL[g][tt], 0, 0, 0);
                    }
                }
            }
        }
    }

    // epilogue per tile: bias+ReLU -> per-wave hsl (C->A transform), then L2
#pragma unroll
    for (int g = 0; g < MAXGE; g++) {
        if (g < ng) {
#pragma unroll
            for (int tt = 0; tt < 4; tt++) {
                int c = tt * 16 + n16;
                float bias = b0[c];
#pragma unroll
                for (int r4 = 0; r4 < 4; r4++)
                    hsl[w][(quad * 4 + r4) * 66 + c] = f2bf(fmaxf(accL[g][tt][r4] + bias, 0.f));
            }
            float4_ acc2[8];
#pragma unroll
            for (int q = 0; q < 8; q++) acc2[q] = (float4_){0.f, 0.f, 0.f, 0.f};
#pragma unroll
            for (int kc = 0; kc < 2; kc++) {
                short8 a2 = *(const short8*)&hsl[w][n16 * 66 + kc * 32 + quad * 8];
#pragma unroll
                for (int tt = 0; tt < 8; tt++)
                    acc2[tt] = __builtin_amdgcn_mfma_f32_16x16x32_bf16(
                        a2, FRAG(w1reg, tt * 2 + kc, lane), acc2[tt], 0, 0, 0);
            }
#pragma unroll
            for (int tt = 0; tt < 8; tt++) {
                int c = tt * 16 + n16;
                float bias = b1[c];
#pragma unroll
                for (int r4 = 0; r4 < 4; r4++) {
                    int p = tile[g] * 64 + w * 16 + quad * 4 + r4;
                    if (p < E) {
                        unsigned short v = f2bf(acc2[tt][r4] + bias);  // no ReLU
                        ef0_bf[(size_t)p * ED + c] = v;
                        ef_bf[(size_t)p * ED + c] = v;
                    }
                }
            }
        }
    }
}

// MFMA MPN step (R4 structure — best measured at 96us), CSR-position order:
// srcp/tgtp are position-indexed; tgtp sorted -> 16 lanes share ~3-5 target
// rows (L1-local ti gathers). ef/msg at position p (contiguous).
__global__ __launch_bounds__(256, 3) void edge_step_k(
    const int* __restrict__ srcp, const int* __restrict__ tgtp,
    const unsigned short* __restrict__ nf0_bf, const unsigned short* __restrict__ nf_bf,
    const unsigned short* __restrict__ ef0_bf, unsigned short* __restrict__ ef_bf,
    unsigned short* __restrict__ msg,
    const unsigned short* __restrict__ w0T, const float* __restrict__ meb0,
    const unsigned short* __restrict__ w1T, const float* __restrict__ meb1,
    const unsigned short* __restrict__ wmT, const float* __restrict__ mnb0,
    int E, int wmsg)
{
    const int t = threadIdx.x;
    const int e0 = blockIdx.x * TS;
    __shared__ unsigned short wreg[16384];     // 32KB weight staging
    __shared__ unsigned short hef[4][2080];    // per-wave band: h(66) then efn(130)

    const int w = t >> 6, lane = t & 63, quad = lane >> 4, n16 = lane & 15;
    int ec = e0 + w * 16 + n16; if (ec >= E) ec = E - 1;
    const int ti = tgtp[ec], sj = srcp[ec];

    const unsigned short* pA[6] = {
        nf0_bf + (size_t)ti * ND + quad * 8,
        nf_bf  + (size_t)ti * ND + quad * 8,
        nf0_bf + (size_t)sj * ND + quad * 8,
        nf_bf  + (size_t)sj * ND + quad * 8,
        ef0_bf + (size_t)ec * ED + quad * 8,
        ef_bf  + (size_t)ec * ED + quad * 8 };

    // ---- edge MLP layer 0: [64x768]x[768->64], K in 3 chunks of 256 ----
    float4_ accL[4];
#pragma unroll
    for (int q = 0; q < 4; q++) accL[q] = (float4_){0.f, 0.f, 0.f, 0.f};
#pragma unroll
    for (int hf = 0; hf < 3; hf++) {
        short8 a8[8];
#pragma unroll
        for (int q2 = 0; q2 < 8; q2++)
            a8[q2] = *(const short8*)(pA[hf * 2 + (q2 >> 2)] + (q2 & 3) * 32);
        stage_frags<4, 8, 768>(w0T, wreg, t, hf * 256);
        __syncthreads();
#pragma unroll
        for (int kc = 0; kc < 8; kc++) {
#pragma unroll
            for (int tt = 0; tt < 4; tt++) {
                short8 b = FRAG(wreg, tt * 8 + kc, lane);
                accL[tt] = __builtin_amdgcn_mfma_f32_16x16x32_bf16(a8[kc], b, accL[tt], 0, 0, 0);
            }
        }
        __syncthreads();
    }

    // L0 epilogue -> h in own-wave band (stride 66), no barrier needed
#pragma unroll
    for (int tt = 0; tt < 4; tt++) {
        int c = tt * 16 + n16;
        float bias = meb0[c];
#pragma unroll
        for (int r4 = 0; r4 < 4; r4++)
            hef[w][(quad * 4 + r4) * 66 + c] = f2bf(fmaxf(accL[tt][r4] + bias, 0.f));
    }

    // ---- edge MLP layer 1: [64x64]x[64->128] ----
    stage_frags<8, 2, 64>(w1T, wreg, t, 0);    // 16KB into wreg
    __syncthreads();
    {
        float4_ acc[8];
#pragma unroll
        for (int q = 0; q < 8; q++) acc[q] = (float4_){0.f, 0.f, 0.f, 0.f};
#pragma unroll
        for (int kc = 0; kc < 2; kc++) {
            short8 a = *(const short8*)&hef[w][n16 * 66 + kc * 32 + quad * 8];
#pragma unroll
            for (int tt = 0; tt < 8; tt++) {
                short8 b = FRAG(wreg, tt * 2 + kc, lane);
                acc[tt] = __builtin_amdgcn_mfma_f32_16x16x32_bf16(a, b, acc[tt], 0, 0, 0);
            }
        }
        // epilogue: efn into own-wave band (stride 130) + global ef store
#pragma unroll
        for (int tt = 0; tt < 8; tt++) {
            int c = tt * 16 + n16;
            float bias = meb1[c];
#pragma unroll
            for (int r4 = 0; r4 < 4; r4++) {
                int row = quad * 4 + r4;
                unsigned short v = f2bf(fmaxf(acc[tt][r4] + bias, 0.f));
                hef[w][row * 130 + c] = v;
                int e = e0 + w * 16 + row;
                if (e < E) ef_bf[(size_t)e * ED + c] = v;
            }
        }
    }
    __syncthreads();

    // ---- node-message MLP: [64x384]x[384->128], K in 3 chunks of 128 ----
    // (skipped on the last step: final nf is never consumed)
    if (wmsg) {
        float4_ accM[8];
#pragma unroll
        for (int q = 0; q < 8; q++) accM[q] = (float4_){0.f, 0.f, 0.f, 0.f};
#pragma unroll
        for (int j = 0; j < 3; j++) {
            short8 a4[4];
            if (j < 2) {
#pragma unroll
                for (int q2 = 0; q2 < 4; q2++)
                    a4[q2] = *(const short8*)(pA[j] + q2 * 32);
            } else {
#pragma unroll
                for (int q2 = 0; q2 < 4; q2++)
                    a4[q2] = *(const short8*)&hef[w][n16 * 130 + q2 * 32 + quad * 8];
            }
            stage_frags<8, 4, 384>(wmT, wreg, t, j * 128);
            __syncthreads();
#pragma unroll
            for (int kc = 0; kc < 4; kc++) {
#pragma unroll
                for (int tt = 0; tt < 8; tt++) {
                    short8 b = FRAG(wreg, tt * 4 + kc, lane);
                    accM[tt] = __builtin_amdgcn_mfma_f32_16x16x32_bf16(a4[kc], b, accM[tt], 0, 0, 0);
                }
            }
            __syncthreads();
        }
#pragma unroll
        for (int tt = 0; tt < 8; tt++) {
            int c = tt * 16 + n16;
            float bias = mnb0[c];
#pragma unroll
            for (int r4 = 0; r4 < 4; r4++) {
                int row = w * 16 + quad * 4 + r4;
                int e = e0 + row;
                if (e < E)
                    msg[(size_t)e * ND + c] = f2bf(fmaxf(accM[tt][r4] + bias, 0.f));
            }
        }
    }
}

// classify: computes at CSR position p, scatters to out[csr_eid[p]].
__global__ __launch_bounds__(256) void classify_k(
    const unsigned short* __restrict__ ef_bf, const int* __restrict__ csr_eid,
    const unsigned short* __restrict__ cw0T, const float* __restrict__ cb0,
    const float* __restrict__ cw1, const float* __restrict__ cb1,
    const float* __restrict__ cw2, const float* __restrict__ cb2,
    float* __restrict__ out, int E)
{
    const int t = threadIdx.x;
    const int e0 = blockIdx.x * TM;
    __shared__ unsigned short h0_bf[TM][66];
    __shared__ float h1[TM][33];

    const int w = t >> 6, lane = t & 63, quad = lane >> 4, n16 = lane & 15;
    const int m = w & 1;
    const int erow = m * 16 + n16;
    int ec = e0 + erow; if (ec >= E) ec = E - 1;
    const unsigned short* pa = ef_bf + (size_t)ec * ED + quad * 8;

    {
        const int cb = (w >> 1) * 32;
        float4_ acc0 = {0.f, 0.f, 0.f, 0.f}, acc1 = acc0;
        const unsigned short* b0p = cw0T + (size_t)(cb + n16) * 128 + quad * 8;
        const unsigned short* b1p = b0p + (size_t)16 * 128;
#pragma unroll
        for (int kc = 0; kc < 4; kc++) {
            short8 a  = *(const short8*)(pa + kc * 32);
            short8 bb0 = *(const short8*)(b0p + kc * 32);
            short8 bb1 = *(const short8*)(b1p + kc * 32);
            acc0 = __builtin_amdgcn_mfma_f32_16x16x32_bf16(a, bb0, acc0, 0, 0, 0);
            acc1 = __builtin_amdgcn_mfma_f32_16x16x32_bf16(a, bb1, acc1, 0, 0, 0);
        }
#pragma unroll
        for (int t2 = 0; t2 < 2; t2++) {
            int c = cb + t2 * 16 + n16;
            float bias = cb0[c];
            float4_ ac = t2 ? acc1 : acc0;
#pragma unroll
            for (int r4 = 0; r4 < 4; r4++)
                h0_bf[m * 16 + quad * 4 + r4][c] = f2bf(fmaxf(ac[r4] + bias, 0.f));
        }
    }
    __syncthreads();

    {
        int c = t & 31;
        int rbase = (t >> 5) * 4;
#pragma unroll
        for (int q = 0; q < 4; q++) {
            int r = rbase + q;
            float acc = cb1[c];
#pragma unroll 8
            for (int k = 0; k < 64; k++) acc += bf2f(h0_bf[r][k]) * cw1[k * 32 + c];
            h1[r][c] = fmaxf(acc, 0.f);
        }
    }
    __syncthreads();

    if (t < TM) {
        int p = e0 + t;
        if (p < E) {
            float a = cb2[0];
#pragma unroll
            for (int k = 0; k < 32; k++) a += h1[t][k] * cw2[k];
            out[csr_eid[p]] = a;
        }
    }
}

extern "C" void kernel_launch(void* const* d_in, const int* in_sizes, int n_in,
                              void* d_out, int out_size, void* d_ws, size_t ws_size,
                              hipStream_t stream)
{
    const float* x    = (const float*)d_in[0];
    const float* ea   = (const float*)d_in[1];
    const int*   eidx = (const int*)d_in[2];
    const float* new0 = (const float*)d_in[3];  const float* neb0 = (const float*)d_in[4];
    const float* new1 = (const float*)d_in[5];  const float* neb1 = (const float*)d_in[6];
    const float* eew0 = (const float*)d_in[7];  const float* eeb0 = (const float*)d_in[8];
    const float* eew1 = (const float*)d_in[9];  const float* eeb1 = (const float*)d_in[10];
    const float* mew0 = (const float*)d_in[11]; const float* meb0 = (const float*)d_in[12];
    const float* mew1 = (const float*)d_in[13]; const float* meb1 = (const float*)d_in[14];
    const float* mnw0 = (const float*)d_in[15]; const float* mnb0 = (const float*)d_in[16];
    const float* cw0  = (const float*)d_in[17]; const float* cb0  = (const float*)d_in[18];
    const float* cw1  = (const float*)d_in[19]; const float* cb1  = (const float*)d_in[20];
    const float* cw2  = (const float*)d_in[21]; const float* cb2  = (const float*)d_in[22];

    const int N = in_sizes[0] / NIN;   // 20000
    const int E = in_sizes[2] / 2;     // 100000
    const int* srcj = eidx;            // edge_index[0] = j (source)
    const int* tgti = eidx + E;        // edge_index[1] = i (target)

    char* wsb = (char*)d_ws;
    unsigned short* nf0_bf = (unsigned short*)wsb;          // N*ND
    unsigned short* nf_bf  = nf0_bf + (size_t)N * ND;
    unsigned short* ef0_bf = nf_bf + (size_t)N * ND;
    unsigned short* ef_bf  = ef0_bf + (size_t)E * ED;
    unsigned short* msg    = ef_bf + (size_t)E * ED;        // E*ND bf16 messages (CSR order)
    unsigned short* w0T  = msg + (size_t)E * ND;            // [64][768]
    unsigned short* w1T  = w0T + 49152;                     // [128][64]
    unsigned short* wmT  = w1T + 8192;                      // [128][384]
    unsigned short* w0eT = wmT + 49152;                     // [64][KPAD]
    unsigned short* w1eT = w0eT + 64 * KPAD;                // [128][64]
    unsigned short* cw0T = w1eT + 8192;                     // [64][128]
    unsigned short* w0nT = cw0T + 8192;                     // [128][128]
    unsigned short* w1nT = w0nT + 16384;                    // [128][128]
    int* deg     = (int*)(w1nT + 16384);                    // N
    int* cursor  = deg + N;                                 // N (contiguous w/ deg)
    int* row_ptr = cursor + N;                              // N+1
    int* csr_eid = row_ptr + (N + 4);                       // E
    int* srcp    = csr_eid + E;                             // E (CSR-order source)
    int* tgtp    = srcp + E;                                // E (CSR-order target, sorted)

    const int eblocks32 = (E + TM - 1) / TM;
    const int nblocks32 = (N + TM - 1) / TM;
    const int ntiles64 = (E + 63) / 64;

    wprep_k<<<(176128 + 255) / 256, 256, 0, stream>>>(mew0, mew1, mnw0, eew0, eew1, cw0,
                                                      new0, new1,
                                                      w0T, w1T, wmT, w0eT, w1eT, cw0T,
                                                      w0nT, w1nT);

    // CSR build (edge_index is constant across all 4 steps)
    zero_k<<<((2 * N) / 4 + 255) / 256, 256, 0, stream>>>((float*)deg, (2 * N) / 4);
    hist_k<<<(E + 255) / 256, 256, 0, stream>>>(tgti, deg, E);
    scan_k<<<1, 256, 0, stream>>>(deg, row_ptr, cursor, N, E);
    scatter_k<<<(E + 255) / 256, 256, 0, stream>>>(tgti, cursor, csr_eid, E);
    permidx_k<<<(E + 255) / 256, 256, 0, stream>>>(csr_eid, srcj, tgti, srcp, tgtp, E);

    node_embed_k<<<nblocks32, 256, 0, stream>>>(x, w0nT, neb0, w1nT, neb1,
                                                nf0_bf, nf_bf, N);
    edge_embed_k<<<GSE, 256, 0, stream>>>(ea, csr_eid, w0eT, eeb0, w1eT, eeb1,
                                          ef0_bf, ef_bf, E, ntiles64);

    for (int s = 0; s < 4; s++) {
        edge_step_k<<<ntiles64, 256, 0, stream>>>(srcp, tgtp, nf0_bf, nf_bf,
                                                  ef0_bf, ef_bf, msg,
                                                  w0T, meb0, w1T, meb1, wmT, mnb0,
                                                  E, (s < 3) ? 1 : 0);
        if (s < 3)
            agg_k<<<(N + 1) / 2, 256, 0, stream>>>(row_ptr, msg, nf_bf, N);
    }

    classify_k<<<eblocks32, 256, 0, stream>>>(ef_bf, csr_eid, cw0T, cb0, cw1, cb1, cw2, cb2,
                                              (float*)d_out, E);
}

// Round 12
// 680.186 us; speedup vs baseline: 1.3670x; 1.0725x over previous
//
#include <hip/hip_runtime.h>
#include <hip/hip_bf16.h>

#define ND 128
#define ED 128
#define NIN 128
#define EIN 291
#define KPAD 320   // EIN padded to multiple of 32 (w0eT row stride)
#define HH 64
#define TM 32      // nodes per block in node-embed / edges per block in classify
#define TS 64      // edges per block in edge_step
#define GSE 768    // grid blocks for edge_embed (3 per CU)
#define MAXGE 3    // max 64-edge tiles per edge_embed block

typedef __attribute__((ext_vector_type(8))) short short8;
typedef __attribute__((ext_vector_type(4))) float float4_;

__device__ __forceinline__ unsigned short f2bf(float f)
{
    union { float f; unsigned u; } v; v.f = f;
    unsigned u = v.u;
    unsigned r = (u + 0x7FFFu + ((u >> 16) & 1u)) >> 16;  // RNE
    return (unsigned short)r;
}
__device__ __forceinline__ float bf2f(unsigned short s)
{
    union { unsigned u; float f; } v; v.u = ((unsigned)s) << 16;
    return v.f;
}

// Stage T N-tiles x KC k-chunks of B (layout [col][K], bf16) into LDS in MFMA
// FRAGMENT ORDER: fragment f=tt*KC+kc occupies 64 consecutive short8 slots.
template<int T, int KC, int K>
__device__ __forceinline__ void stage_frags(const unsigned short* __restrict__ src,
                                            unsigned short* __restrict__ wreg,
                                            int t, int k0)
{
    constexpr int TOT = T * KC * 64;
#pragma unroll
    for (int it = 0; it < TOT / 256; it++) {
        int idx = it * 256 + t;
        int f = idx >> 6, l = idx & 63;
        int col = (f / KC) * 16 + (l & 15);
        int k = (f % KC) * 32 + ((l >> 4) * 8);
        *(short8*)&wreg[idx * 8] = *(const short8*)&src[(size_t)col * K + k0 + k];
    }
}
#define FRAG(wreg, f, lane) (*(const short8*)&(wreg)[(((f) << 6) + (lane)) * 8])

// Zero a buffer (16B granules).
__global__ __launch_bounds__(256) void zero_k(float* __restrict__ p, int n4)
{
    int idx = blockIdx.x * 256 + threadIdx.x;
    if (idx < n4) ((float4*)p)[idx] = make_float4(0.f, 0.f, 0.f, 0.f);
}

// ---- CSR build (once per launch; edge_index is constant across the 4 steps) ----
__global__ __launch_bounds__(256) void hist_k(const int* __restrict__ tgti,
                                              int* __restrict__ deg, int E)
{
    int e = blockIdx.x * 256 + threadIdx.x;
    if (e < E) atomicAdd(&deg[tgti[e]], 1);
}

// Single-block exclusive scan over deg[0..N) -> row_ptr & cursor.
__global__ __launch_bounds__(256) void scan_k(const int* __restrict__ deg,
                                              int* __restrict__ row_ptr,
                                              int* __restrict__ cursor, int N, int E)
{
    __shared__ int part[256];
    const int t = threadIdx.x;
    const int chunk = (N + 255) / 256;
    const int base = t * chunk;
    int s = 0;
    for (int k = 0; k < chunk; k++) { int idx = base + k; if (idx < N) s += deg[idx]; }
    part[t] = s;
    __syncthreads();
    for (int off = 1; off < 256; off <<= 1) {
        int v = (t >= off) ? part[t - off] : 0;
        __syncthreads();
        part[t] += v;
        __syncthreads();
    }
    int run = (t == 0) ? 0 : part[t - 1];
    for (int k = 0; k < chunk; k++) {
        int idx = base + k;
        if (idx < N) { row_ptr[idx] = run; cursor[idx] = run; run += deg[idx]; }
    }
    if (t == 255) row_ptr[N] = E;
}

__global__ __launch_bounds__(256) void scatter_k(const int* __restrict__ tgti,
                                                 int* __restrict__ cursor,
                                                 int* __restrict__ csr_eid, int E)
{
    int e = blockIdx.x * 256 + threadIdx.x;
    if (e < E) {
        int p = atomicAdd(&cursor[tgti[e]], 1);
        csr_eid[p] = e;
    }
}

// Positional src/tgt arrays in CSR (target-sorted) order.
__global__ __launch_bounds__(256) void permidx_k(const int* __restrict__ csr_eid,
                                                 const int* __restrict__ srcj,
                                                 const int* __restrict__ tgti,
                                                 int* __restrict__ srcp,
                                                 int* __restrict__ tgtp, int E)
{
    int p = blockIdx.x * 256 + threadIdx.x;
    if (p < E) {
        int e = csr_eid[p];
        srcp[p] = srcj[e];
        tgtp[p] = tgti[e];
    }
}

// Boundary fixup after fused-aggregation edge_step: nodes whose CSR segment
// crosses a 32-position window boundary were accumulated via fp32 atomics in
// nfx — convert to bf16 and re-zero. deg-0 nodes get nf=0.
__global__ __launch_bounds__(256) void fixup_k(const int* __restrict__ row_ptr,
                                               float* __restrict__ nfx,
                                               unsigned short* __restrict__ nf_out, int N)
{
    int n = blockIdx.x * 2 + (threadIdx.x >> 7);
    int c = threadIdx.x & 127;
    if (n >= N) return;
    int beg = row_ptr[n], end = row_ptr[n + 1];
    if (beg == end) { nf_out[(size_t)n * ND + c] = 0; return; }
    if ((beg >> 5) != ((end - 1) >> 5)) {
        size_t idx = (size_t)n * ND + c;
        nf_out[idx] = f2bf(nfx[idx]);
        nfx[idx] = 0.f;
    }
}

// One-time weight prep: transpose + fp32->bf16 (+ zero-pad K for edge-embed L1).
__global__ __launch_bounds__(256) void wprep_k(
    const float* __restrict__ mew0, const float* __restrict__ mew1, const float* __restrict__ mnw0,
    const float* __restrict__ eew0, const float* __restrict__ eew1, const float* __restrict__ cw0,
    const float* __restrict__ new0, const float* __restrict__ new1,
    unsigned short* __restrict__ w0T, unsigned short* __restrict__ w1T,
    unsigned short* __restrict__ wmT, unsigned short* __restrict__ w0eT,
    unsigned short* __restrict__ w1eT, unsigned short* __restrict__ cw0T,
    unsigned short* __restrict__ w0nT, unsigned short* __restrict__ w1nT)
{
    int idx = blockIdx.x * 256 + threadIdx.x;
    if (idx < 49152) {
        int c = idx / 768, k = idx % 768;
        w0T[idx] = f2bf(mew0[k * 64 + c]);
    } else if (idx < 57344) {
        int j = idx - 49152; int c = j / 64, k = j % 64;
        w1T[j] = f2bf(mew1[k * 128 + c]);
    } else if (idx < 106496) {
        int j = idx - 57344; int c = j / 384, k = j % 384;
        wmT[j] = f2bf(mnw0[k * 128 + c]);
    } else if (idx < 126976) {
        int j = idx - 106496; int c = j / KPAD, k = j % KPAD;
        w0eT[j] = (k < EIN) ? f2bf(eew0[k * 64 + c]) : (unsigned short)0;
    } else if (idx < 135168) {
        int j = idx - 126976; int c = j / 64, k = j % 64;
        w1eT[j] = f2bf(eew1[k * 128 + c]);
    } else if (idx < 143360) {
        int j = idx - 135168; int c = j / 128, k = j % 128;
        cw0T[j] = f2bf(cw0[k * 64 + c]);
    } else if (idx < 159744) {
        int j = idx - 143360; int c = j / 128, k = j % 128;
        w0nT[j] = f2bf(new0[k * 128 + c]);
    } else if (idx < 176128) {
        int j = idx - 159744; int c = j / 128, k = j % 128;
        w1nT[j] = f2bf(new1[k * 128 + c]);
    }
}

// MFMA node embed: 32 nodes/block (unchanged; writes nf0 + nfA).
__global__ __launch_bounds__(256) void node_embed_k(
    const float* __restrict__ x,
    const unsigned short* __restrict__ w0nT, const float* __restrict__ b0,
    const unsigned short* __restrict__ w1nT, const float* __restrict__ b1,
    unsigned short* __restrict__ nf0_bf, unsigned short* __restrict__ nf_bf, int N)
{
    const int t = threadIdx.x;
    const int n0 = blockIdx.x * TM;
    __shared__ unsigned short wreg[8192];
    __shared__ unsigned short xin[TM][130];
    __shared__ unsigned short h_bf[TM][130];

#pragma unroll
    for (int it = 0; it < 4; it++) {
        int idx = it * 256 + t;
        int r = idx >> 5, c4 = idx & 31;
        int node = n0 + r; if (node >= N) node = N - 1;
        float4 v = *(const float4*)(x + (size_t)node * NIN + c4 * 4);
        unsigned lo = (unsigned)f2bf(v.x) | ((unsigned)f2bf(v.y) << 16);
        unsigned hi = (unsigned)f2bf(v.z) | ((unsigned)f2bf(v.w) << 16);
        *(uint2*)&xin[r][c4 * 4] = make_uint2(lo, hi);
    }

    const int w = t >> 6, lane = t & 63, quad = lane >> 4, n16 = lane & 15;
    const int m = w & 1, nh = w >> 1;

    float4_ acc[4];
#pragma unroll
    for (int q = 0; q < 4; q++) acc[q] = (float4_){0.f, 0.f, 0.f, 0.f};
#pragma unroll
    for (int hf = 0; hf < 2; hf++) {
        stage_frags<8, 2, 128>(w0nT, wreg, t, hf * 64);
        __syncthreads();
#pragma unroll
        for (int kc = 0; kc < 2; kc++) {
            short8 a = *(const short8*)&xin[m * 16 + n16][hf * 64 + kc * 32 + quad * 8];
#pragma unroll
            for (int tt = 0; tt < 4; tt++) {
                short8 b = FRAG(wreg, (nh * 4 + tt) * 2 + kc, lane);
                acc[tt] = __builtin_amdgcn_mfma_f32_16x16x32_bf16(a, b, acc[tt], 0, 0, 0);
            }
        }
        __syncthreads();
    }
#pragma unroll
    for (int tt = 0; tt < 4; tt++) {
        int c = nh * 64 + tt * 16 + n16;
        float bias = b0[c];
#pragma unroll
        for (int r4 = 0; r4 < 4; r4++)
            h_bf[m * 16 + quad * 4 + r4][c] = f2bf(fmaxf(acc[tt][r4] + bias, 0.f));
    }
    __syncthreads();

    float4_ acc2[4];
#pragma unroll
    for (int q = 0; q < 4; q++) acc2[q] = (float4_){0.f, 0.f, 0.f, 0.f};
#pragma unroll
    for (int hf = 0; hf < 2; hf++) {
        stage_frags<8, 2, 128>(w1nT, wreg, t, hf * 64);
        __syncthreads();
#pragma unroll
        for (int kc = 0; kc < 2; kc++) {
            short8 a = *(const short8*)&h_bf[m * 16 + n16][hf * 64 + kc * 32 + quad * 8];
#pragma unroll
            for (int tt = 0; tt < 4; tt++) {
                short8 b = FRAG(wreg, (nh * 4 + tt) * 2 + kc, lane);
                acc2[tt] = __builtin_amdgcn_mfma_f32_16x16x32_bf16(a, b, acc2[tt], 0, 0, 0);
            }
        }
        __syncthreads();
    }
#pragma unroll
    for (int tt = 0; tt < 4; tt++) {
        int c = nh * 64 + tt * 16 + n16;
        float bias = b1[c];
#pragma unroll
        for (int r4 = 0; r4 < 4; r4++) {
            int row = m * 16 + quad * 4 + r4;
            int node = n0 + row;
            if (node < N) {
                unsigned short v = f2bf(acc2[tt][r4] + bias);
                nf0_bf[(size_t)node * ND + c] = v;
                nf_bf[(size_t)node * ND + c] = v;
            }
        }
    }
}

// MFMA edge embed (co-resident 768 blocks, 3 tiles each) + CSR-permuted rows.
__global__ __launch_bounds__(256, 3) void edge_embed_k(
    const float* __restrict__ ea, const int* __restrict__ csr_eid,
    const unsigned short* __restrict__ w0eT, const float* __restrict__ b0,
    const unsigned short* __restrict__ w1eT, const float* __restrict__ b1,
    unsigned short* __restrict__ ef0_bf, unsigned short* __restrict__ ef_bf,
    int E, int ntiles)
{
    const int t = threadIdx.x;
    __shared__ unsigned short w0reg[10240];   // 20KB: one K-half (T=4, KC=5)
    __shared__ unsigned short w1reg[8192];    // 16KB: w1e full (T=8, KC=2)
    __shared__ unsigned short hsl[4][16 * 66];

    const int w = t >> 6, lane = t & 63, quad = lane >> 4, n16 = lane & 15;

    stage_frags<8, 2, 64>(w1eT, w1reg, t, 0);   // covered by first barrier below

    int ng = 0;
    int tile[MAXGE];
#pragma unroll
    for (int g = 0; g < MAXGE; g++) {
        int tl = blockIdx.x + g * GSE;
        if (tl < ntiles) { tile[g] = tl; ng = g + 1; }
        else tile[g] = 0;
    }

    float4_ accL[MAXGE][4];
#pragma unroll
    for (int g = 0; g < MAXGE; g++)
#pragma unroll
        for (int q = 0; q < 4; q++) accL[g][q] = (float4_){0.f, 0.f, 0.f, 0.f};

#pragma unroll
    for (int hf = 0; hf < 2; hf++) {
        __syncthreads();
        stage_frags<4, 5, KPAD>(w0eT, w0reg, t, hf * 160);
        __syncthreads();
#pragma unroll
        for (int g = 0; g < MAXGE; g++) {
            if (g < ng) {
                int p = tile[g] * 64 + w * 16 + n16; if (p >= E) p = E - 1;
                const float* src = ea + (size_t)csr_eid[p] * EIN;
#pragma unroll
                for (int kc = 0; kc < 5; kc++) {
                    int k = hf * 160 + kc * 32 + quad * 8;
                    union { short8 s; uint4 u; } av;
                    if (k + 8 <= EIN) {
                        float4 v0 = *(const float4*)(src + k);
                        float4 v1 = *(const float4*)(src + k + 4);
                        av.u.x = (unsigned)f2bf(v0.x) | ((unsigned)f2bf(v0.y) << 16);
                        av.u.y = (unsigned)f2bf(v0.z) | ((unsigned)f2bf(v0.w) << 16);
                        av.u.z = (unsigned)f2bf(v1.x) | ((unsigned)f2bf(v1.y) << 16);
                        av.u.w = (unsigned)f2bf(v1.z) | ((unsigned)f2bf(v1.w) << 16);
                    } else {
                        unsigned short vv[8];
#pragma unroll
                        for (int j = 0; j < 8; j++)
                            vv[j] = (k + j < EIN) ? f2bf(src[k + j]) : (unsigned short)0;
                        av.u.x = (unsigned)vv[0] | ((unsigned)vv[1] << 16);
                        av.u.y = (unsigned)vv[2] | ((unsigned)vv[3] << 16);
                        av.u.z = (unsigned)vv[4] | ((unsigned)vv[5] << 16);
                        av.u.w = (unsigned)vv[6] | ((unsigned)vv[7] << 16);
                    }
#pragma unroll
                    for (int tt = 0; tt < 4; tt++) {
                        short8 b = FRAG(w0reg, tt * 5 + kc, lane);
                        accL[g][tt] = __builtin_amdgcn_mfma_f32_16x16x32_bf16(av.s, b, accL[g][tt], 0, 0, 0);
                    }
                }
            }
        }
    }

    // epilogue per tile: bias+ReLU -> per-wave hsl (C->A transform), then L2
#pragma unroll
    for (int g = 0; g < MAXGE; g++) {
        if (g < ng) {
#pragma unroll
            for (int tt = 0; tt < 4; tt++) {
                int c = tt * 16 + n16;
                float bias = b0[c];
#pragma unroll
                for (int r4 = 0; r4 < 4; r4++)
                    hsl[w][(quad * 4 + r4) * 66 + c] = f2bf(fmaxf(accL[g][tt][r4] + bias, 0.f));
            }
            float4_ acc2[8];
#pragma unroll
            for (int q = 0; q < 8; q++) acc2[q] = (float4_){0.f, 0.f, 0.f, 0.f};
#pragma unroll
            for (int kc = 0; kc < 2; kc++) {
                short8 a2 = *(const short8*)&hsl[w][n16 * 66 + kc * 32 + quad * 8];
#pragma unroll
                for (int tt = 0; tt < 8; tt++)
                    acc2[tt] = __builtin_amdgcn_mfma_f32_16x16x32_bf16(
                        a2, FRAG(w1reg, tt * 2 + kc, lane), acc2[tt], 0, 0, 0);
            }
#pragma unroll
            for (int tt = 0; tt < 8; tt++) {
                int c = tt * 16 + n16;
                float bias = b1[c];
#pragma unroll
                for (int r4 = 0; r4 < 4; r4++) {
                    int p = tile[g] * 64 + w * 16 + quad * 4 + r4;
                    if (p < E) {
                        unsigned short v = f2bf(acc2[tt][r4] + bias);  // no ReLU
                        ef0_bf[(size_t)p * ED + c] = v;
                        ef_bf[(size_t)p * ED + c] = v;
                    }
                }
            }
        }
    }
}

// MFMA MPN step, CSR order + FUSED AGGREGATION: message tile stashed in wreg
// (free after last weight phase), then per-column segment scan over the
// block's 64 sorted positions. Segments fully inside a 32-position window ->
// direct bf16 nf store; window-crossing segments -> fp32 atomicAdd into nfx
// (resolved by fixup_k). nf double-buffered (reads nf_in, writes nf_out).
__global__ __launch_bounds__(256, 3) void edge_step_k(
    const int* __restrict__ srcp, const int* __restrict__ tgtp,
    const unsigned short* __restrict__ nf0_bf, const unsigned short* __restrict__ nf_in,
    const unsigned short* __restrict__ ef0_bf, unsigned short* __restrict__ ef_bf,
    unsigned short* __restrict__ nf_out, float* __restrict__ nfx,
    const unsigned short* __restrict__ w0T, const float* __restrict__ meb0,
    const unsigned short* __restrict__ w1T, const float* __restrict__ meb1,
    const unsigned short* __restrict__ wmT, const float* __restrict__ mnb0,
    int E, int wmsg)
{
    const int t = threadIdx.x;
    const int e0 = blockIdx.x * TS;
    __shared__ unsigned short wreg[16384];     // 32KB weight staging / msg tile
    __shared__ unsigned short hef[4][2080];    // per-wave band: h(66) then efn(130)

    const int w = t >> 6, lane = t & 63, quad = lane >> 4, n16 = lane & 15;
    int ec = e0 + w * 16 + n16; if (ec >= E) ec = E - 1;
    const int ti = tgtp[ec], sj = srcp[ec];

    const unsigned short* pA[6] = {
        nf0_bf + (size_t)ti * ND + quad * 8,
        nf_in  + (size_t)ti * ND + quad * 8,
        nf0_bf + (size_t)sj * ND + quad * 8,
        nf_in  + (size_t)sj * ND + quad * 8,
        ef0_bf + (size_t)ec * ED + quad * 8,
        ef_bf  + (size_t)ec * ED + quad * 8 };

    // ---- edge MLP layer 0: [64x768]x[768->64], K in 3 chunks of 256 ----
    float4_ accL[4];
#pragma unroll
    for (int q = 0; q < 4; q++) accL[q] = (float4_){0.f, 0.f, 0.f, 0.f};
#pragma unroll
    for (int hf = 0; hf < 3; hf++) {
        short8 a8[8];
#pragma unroll
        for (int q2 = 0; q2 < 8; q2++)
            a8[q2] = *(const short8*)(pA[hf * 2 + (q2 >> 2)] + (q2 & 3) * 32);
        stage_frags<4, 8, 768>(w0T, wreg, t, hf * 256);
        __syncthreads();
#pragma unroll
        for (int kc = 0; kc < 8; kc++) {
#pragma unroll
            for (int tt = 0; tt < 4; tt++) {
                short8 b = FRAG(wreg, tt * 8 + kc, lane);
                accL[tt] = __builtin_amdgcn_mfma_f32_16x16x32_bf16(a8[kc], b, accL[tt], 0, 0, 0);
            }
        }
        __syncthreads();
    }

    // L0 epilogue -> h in own-wave band (stride 66), no barrier needed
#pragma unroll
    for (int tt = 0; tt < 4; tt++) {
        int c = tt * 16 + n16;
        float bias = meb0[c];
#pragma unroll
        for (int r4 = 0; r4 < 4; r4++)
            hef[w][(quad * 4 + r4) * 66 + c] = f2bf(fmaxf(accL[tt][r4] + bias, 0.f));
    }

    // ---- edge MLP layer 1: [64x64]x[64->128] ----
    stage_frags<8, 2, 64>(w1T, wreg, t, 0);    // 16KB into wreg
    __syncthreads();
    {
        float4_ acc[8];
#pragma unroll
        for (int q = 0; q < 8; q++) acc[q] = (float4_){0.f, 0.f, 0.f, 0.f};
#pragma unroll
        for (int kc = 0; kc < 2; kc++) {
            short8 a = *(const short8*)&hef[w][n16 * 66 + kc * 32 + quad * 8];
#pragma unroll
            for (int tt = 0; tt < 8; tt++) {
                short8 b = FRAG(wreg, tt * 2 + kc, lane);
                acc[tt] = __builtin_amdgcn_mfma_f32_16x16x32_bf16(a, b, acc[tt], 0, 0, 0);
            }
        }
        // epilogue: efn into own-wave band (stride 130) + global ef store
#pragma unroll
        for (int tt = 0; tt < 8; tt++) {
            int c = tt * 16 + n16;
            float bias = meb1[c];
#pragma unroll
            for (int r4 = 0; r4 < 4; r4++) {
                int row = quad * 4 + r4;
                unsigned short v = f2bf(fmaxf(acc[tt][r4] + bias, 0.f));
                hef[w][row * 130 + c] = v;
                int e = e0 + w * 16 + row;
                if (e < E) ef_bf[(size_t)e * ED + c] = v;
            }
        }
    }
    __syncthreads();

    // ---- node-message MLP: [64x384]x[384->128], K in 3 chunks of 128 ----
    // (skipped on the last step: final nf is never consumed)
    if (wmsg) {
        float4_ accM[8];
#pragma unroll
        for (int q = 0; q < 8; q++) accM[q] = (float4_){0.f, 0.f, 0.f, 0.f};
#pragma unroll
        for (int j = 0; j < 3; j++) {
            short8 a4[4];
            if (j < 2) {
#pragma unroll
                for (int q2 = 0; q2 < 4; q2++)
                    a4[q2] = *(const short8*)(pA[j] + q2 * 32);
            } else {
#pragma unroll
                for (int q2 = 0; q2 < 4; q2++)
                    a4[q2] = *(const short8*)&hef[w][n16 * 130 + q2 * 32 + quad * 8];
            }
            stage_frags<8, 4, 384>(wmT, wreg, t, j * 128);
            __syncthreads();
#pragma unroll
            for (int kc = 0; kc < 4; kc++) {
#pragma unroll
                for (int tt = 0; tt < 8; tt++) {
                    short8 b = FRAG(wreg, tt * 4 + kc, lane);
                    accM[tt] = __builtin_amdgcn_mfma_f32_16x16x32_bf16(a4[kc], b, accM[tt], 0, 0, 0);
                }
            }
            __syncthreads();
        }

        // ---- fused aggregation ----
        // stash msg tile (bias+ReLU, bf16) into wreg as [64][132]
#pragma unroll
        for (int tt = 0; tt < 8; tt++) {
            int c = tt * 16 + n16;
            float bias = mnb0[c];
#pragma unroll
            for (int r4 = 0; r4 < 4; r4++) {
                int row = w * 16 + quad * 4 + r4;
                wreg[row * 132 + c] = f2bf(fmaxf(accM[tt][r4] + bias, 0.f));
            }
        }
        // stage tgts for p = e0-1 .. e0+64 into int scratch (hef area is free)
        int* tg = (int*)&hef[0][0];
        if (t < 66) {
            int p = e0 - 1 + t;
            tg[t] = (p >= 0 && p < E) ? tgtp[p] : -1;
        }
        __syncthreads();
        {
            int c = t & 127, half = t >> 7;
            int r0 = half * 32;
            float acc = 0.f;
            int rs = 0;
            for (int r = 0; r < 32; r++) {
                int p = e0 + r0 + r;
                if (p >= E) break;
                int n = tg[r0 + r + 1];
                acc += bf2f(wreg[(r0 + r) * 132 + c]);
                bool end_here = (tg[r0 + r + 2] != n);
                if (end_here) {
                    bool beg_in = (rs > 0) || (tg[r0] != n);
                    if (beg_in) nf_out[(size_t)n * ND + c] = f2bf(acc);
                    else        atomicAdd(&nfx[(size_t)n * ND + c], acc);
                    acc = 0.f; rs = r + 1;
                } else if (r == 31) {
                    atomicAdd(&nfx[(size_t)n * ND + c], acc);
                }
            }
        }
    }
}

// classify: computes at CSR position p, scatters to out[csr_eid[p]].
__global__ __launch_bounds__(256) void classify_k(
    const unsigned short* __restrict__ ef_bf, const int* __restrict__ csr_eid,
    const unsigned short* __restrict__ cw0T, const float* __restrict__ cb0,
    const float* __restrict__ cw1, const float* __restrict__ cb1,
    const float* __restrict__ cw2, const float* __restrict__ cb2,
    float* __restrict__ out, int E)
{
    const int t = threadIdx.x;
    const int e0 = blockIdx.x * TM;
    __shared__ unsigned short h0_bf[TM][66];
    __shared__ float h1[TM][33];

    const int w = t >> 6, lane = t & 63, quad = lane >> 4, n16 = lane & 15;
    const int m = w & 1;
    const int erow = m * 16 + n16;
    int ec = e0 + erow; if (ec >= E) ec = E - 1;
    const unsigned short* pa = ef_bf + (size_t)ec * ED + quad * 8;

    {
        const int cb = (w >> 1) * 32;
        float4_ acc0 = {0.f, 0.f, 0.f, 0.f}, acc1 = acc0;
        const unsigned short* b0p = cw0T + (size_t)(cb + n16) * 128 + quad * 8;
        const unsigned short* b1p = b0p + (size_t)16 * 128;
#pragma unroll
        for (int kc = 0; kc < 4; kc++) {
            short8 a  = *(const short8*)(pa + kc * 32);
            short8 bb0 = *(const short8*)(b0p + kc * 32);
            short8 bb1 = *(const short8*)(b1p + kc * 32);
            acc0 = __builtin_amdgcn_mfma_f32_16x16x32_bf16(a, bb0, acc0, 0, 0, 0);
            acc1 = __builtin_amdgcn_mfma_f32_16x16x32_bf16(a, bb1, acc1, 0, 0, 0);
        }
#pragma unroll
        for (int t2 = 0; t2 < 2; t2++) {
            int c = cb + t2 * 16 + n16;
            float bias = cb0[c];
            float4_ ac = t2 ? acc1 : acc0;
#pragma unroll
            for (int r4 = 0; r4 < 4; r4++)
                h0_bf[m * 16 + quad * 4 + r4][c] = f2bf(fmaxf(ac[r4] + bias, 0.f));
        }
    }
    __syncthreads();

    {
        int c = t & 31;
        int rbase = (t >> 5) * 4;
#pragma unroll
        for (int q = 0; q < 4; q++) {
            int r = rbase + q;
            float acc = cb1[c];
#pragma unroll 8
            for (int k = 0; k < 64; k++) acc += bf2f(h0_bf[r][k]) * cw1[k * 32 + c];
            h1[r][c] = fmaxf(acc, 0.f);
        }
    }
    __syncthreads();

    if (t < TM) {
        int p = e0 + t;
        if (p < E) {
            float a = cb2[0];
#pragma unroll
            for (int k = 0; k < 32; k++) a += h1[t][k] * cw2[k];
            out[csr_eid[p]] = a;
        }
    }
}

extern "C" void kernel_launch(void* const* d_in, const int* in_sizes, int n_in,
                              void* d_out, int out_size, void* d_ws, size_t ws_size,
                              hipStream_t stream)
{
    const float* x    = (const float*)d_in[0];
    const float* ea   = (const float*)d_in[1];
    const int*   eidx = (const int*)d_in[2];
    const float* new0 = (const float*)d_in[3];  const float* neb0 = (const float*)d_in[4];
    const float* new1 = (const float*)d_in[5];  const float* neb1 = (const float*)d_in[6];
    const float* eew0 = (const float*)d_in[7];  const float* eeb0 = (const float*)d_in[8];
    const float* eew1 = (const float*)d_in[9];  const float* eeb1 = (const float*)d_in[10];
    const float* mew0 = (const float*)d_in[11]; const float* meb0 = (const float*)d_in[12];
    const float* mew1 = (const float*)d_in[13]; const float* meb1 = (const float*)d_in[14];
    const float* mnw0 = (const float*)d_in[15]; const float* mnb0 = (const float*)d_in[16];
    const float* cw0  = (const float*)d_in[17]; const float* cb0  = (const float*)d_in[18];
    const float* cw1  = (const float*)d_in[19]; const float* cb1  = (const float*)d_in[20];
    const float* cw2  = (const float*)d_in[21]; const float* cb2  = (const float*)d_in[22];

    const int N = in_sizes[0] / NIN;   // 20000
    const int E = in_sizes[2] / 2;     // 100000
    const int* srcj = eidx;            // edge_index[0] = j (source)
    const int* tgti = eidx + E;        // edge_index[1] = i (target)

    char* wsb = (char*)d_ws;
    unsigned short* nf0_bf = (unsigned short*)wsb;          // N*ND
    unsigned short* nfA    = nf0_bf + (size_t)N * ND;       // N*ND (read buf)
    unsigned short* ef0_bf = nfA + (size_t)N * ND;
    unsigned short* ef_bf  = ef0_bf + (size_t)E * ED;
    // former msg slot (E*ND shorts = 25.6MB) now holds nfB (5.1MB) + nfx (10.2MB)
    unsigned short* slot   = ef_bf + (size_t)E * ED;
    unsigned short* nfB    = slot;                          // N*ND bf16 (write buf)
    float*          nfx    = (float*)(slot + (size_t)N * ND); // N*ND fp32 atomics
    unsigned short* w0T  = slot + (size_t)E * ND;           // [64][768]
    unsigned short* w1T  = w0T + 49152;                     // [128][64]
    unsigned short* wmT  = w1T + 8192;                      // [128][384]
    unsigned short* w0eT = wmT + 49152;                     // [64][KPAD]
    unsigned short* w1eT = w0eT + 64 * KPAD;                // [128][64]
    unsigned short* cw0T = w1eT + 8192;                     // [64][128]
    unsigned short* w0nT = cw0T + 8192;                     // [128][128]
    unsigned short* w1nT = w0nT + 16384;                    // [128][128]
    int* deg     = (int*)(w1nT + 16384);                    // N
    int* cursor  = deg + N;                                 // N (contiguous w/ deg)
    int* row_ptr = cursor + N;                              // N+1
    int* csr_eid = row_ptr + (N + 4);                       // E
    int* srcp    = csr_eid + E;                             // E (CSR-order source)
    int* tgtp    = srcp + E;                                // E (CSR-order target, sorted)

    const int eblocks32 = (E + TM - 1) / TM;
    const int nblocks32 = (N + TM - 1) / TM;
    const int ntiles64 = (E + 63) / 64;

    wprep_k<<<(176128 + 255) / 256, 256, 0, stream>>>(mew0, mew1, mnw0, eew0, eew1, cw0,
                                                      new0, new1,
                                                      w0T, w1T, wmT, w0eT, w1eT, cw0T,
                                                      w0nT, w1nT);

    // CSR build (edge_index is constant across all 4 steps)
    zero_k<<<((2 * N) / 4 + 255) / 256, 256, 0, stream>>>((float*)deg, (2 * N) / 4);
    hist_k<<<(E + 255) / 256, 256, 0, stream>>>(tgti, deg, E);
    scan_k<<<1, 256, 0, stream>>>(deg, row_ptr, cursor, N, E);
    scatter_k<<<(E + 255) / 256, 256, 0, stream>>>(tgti, cursor, csr_eid, E);
    permidx_k<<<(E + 255) / 256, 256, 0, stream>>>(csr_eid, srcj, tgti, srcp, tgtp, E);

    // zero the fp32 atomic buffer once (fixup re-zeroes what it uses)
    zero_k<<<((N * ND) / 4 + 255) / 256, 256, 0, stream>>>(nfx, (N * ND) / 4);

    node_embed_k<<<nblocks32, 256, 0, stream>>>(x, w0nT, neb0, w1nT, neb1,
                                                nf0_bf, nfA, N);
    edge_embed_k<<<GSE, 256, 0, stream>>>(ea, csr_eid, w0eT, eeb0, w1eT, eeb1,
                                          ef0_bf, ef_bf, E, ntiles64);

    unsigned short* nfR = nfA;
    unsigned short* nfW = nfB;
    for (int s = 0; s < 4; s++) {
        edge_step_k<<<ntiles64, 256, 0, stream>>>(srcp, tgtp, nf0_bf, nfR,
                                                  ef0_bf, ef_bf, nfW, nfx,
                                                  w0T, meb0, w1T, meb1, wmT, mnb0,
                                                  E, (s < 3) ? 1 : 0);
        if (s < 3) {
            fixup_k<<<(N + 1) / 2, 256, 0, stream>>>(row_ptr, nfx, nfW, N);
            unsigned short* tmp = nfR; nfR = nfW; nfW = tmp;
        }
    }

    classify_k<<<eblocks32, 256, 0, stream>>>(ef_bf, csr_eid, cw0T, cb0, cw1, cb1, cw2, cb2,
                                              (float*)d_out, E);
}

// Round 13
// 664.037 us; speedup vs baseline: 1.4002x; 1.0243x over previous
//
#include <hip/hip_runtime.h>
#include <hip/hip_bf16.h>

#define ND 128
#define ED 128
#define NIN 128
#define EIN 291
#define KPAD 320   // EIN padded to multiple of 32 (w0eT row stride)
#define HH 64
#define TM 32      // nodes per block in node-embed / edges per block in classify
#define TS 64      // edges per block in edge_step
#define GSE 768    // grid blocks for edge_embed (3 per CU)
#define MAXGE 3    // max 64-edge tiles per edge_embed block

typedef __attribute__((ext_vector_type(8))) short short8;
typedef __attribute__((ext_vector_type(4))) float float4_;

__device__ __forceinline__ unsigned short f2bf(float f)
{
    union { float f; unsigned u; } v; v.f = f;
    unsigned u = v.u;
    unsigned r = (u + 0x7FFFu + ((u >> 16) & 1u)) >> 16;  // RNE
    return (unsigned short)r;
}
__device__ __forceinline__ float bf2f(unsigned short s)
{
    union { unsigned u; float f; } v; v.u = ((unsigned)s) << 16;
    return v.f;
}

// Stage T N-tiles x KC k-chunks of B (layout [col][K], bf16) into LDS in MFMA
// FRAGMENT ORDER: fragment f=tt*KC+kc occupies 64 consecutive short8 slots.
template<int T, int KC, int K>
__device__ __forceinline__ void stage_frags(const unsigned short* __restrict__ src,
                                            unsigned short* __restrict__ wreg,
                                            int t, int k0)
{
    constexpr int TOT = T * KC * 64;
#pragma unroll
    for (int it = 0; it < TOT / 256; it++) {
        int idx = it * 256 + t;
        int f = idx >> 6, l = idx & 63;
        int col = (f / KC) * 16 + (l & 15);
        int k = (f % KC) * 32 + ((l >> 4) * 8);
        *(short8*)&wreg[idx * 8] = *(const short8*)&src[(size_t)col * K + k0 + k];
    }
}
#define FRAG(wreg, f, lane) (*(const short8*)&(wreg)[(((f) << 6) + (lane)) * 8])

// Zero a buffer (16B granules).
__global__ __launch_bounds__(256) void zero_k(float* __restrict__ p, int n4)
{
    int idx = blockIdx.x * 256 + threadIdx.x;
    if (idx < n4) ((float4*)p)[idx] = make_float4(0.f, 0.f, 0.f, 0.f);
}

// ---- CSR build (once per launch; edge_index is constant across the 4 steps) ----
__global__ __launch_bounds__(256) void hist_k(const int* __restrict__ tgti,
                                              int* __restrict__ deg, int E)
{
    int e = blockIdx.x * 256 + threadIdx.x;
    if (e < E) atomicAdd(&deg[tgti[e]], 1);
}

// Single-block exclusive scan over deg[0..N) -> row_ptr & cursor.
__global__ __launch_bounds__(256) void scan_k(const int* __restrict__ deg,
                                              int* __restrict__ row_ptr,
                                              int* __restrict__ cursor, int N, int E)
{
    __shared__ int part[256];
    const int t = threadIdx.x;
    const int chunk = (N + 255) / 256;
    const int base = t * chunk;
    int s = 0;
    for (int k = 0; k < chunk; k++) { int idx = base + k; if (idx < N) s += deg[idx]; }
    part[t] = s;
    __syncthreads();
    for (int off = 1; off < 256; off <<= 1) {
        int v = (t >= off) ? part[t - off] : 0;
        __syncthreads();
        part[t] += v;
        __syncthreads();
    }
    int run = (t == 0) ? 0 : part[t - 1];
    for (int k = 0; k < chunk; k++) {
        int idx = base + k;
        if (idx < N) { row_ptr[idx] = run; cursor[idx] = run; run += deg[idx]; }
    }
    if (t == 255) row_ptr[N] = E;
}

__global__ __launch_bounds__(256) void scatter_k(const int* __restrict__ tgti,
                                                 int* __restrict__ cursor,
                                                 int* __restrict__ csr_eid, int E)
{
    int e = blockIdx.x * 256 + threadIdx.x;
    if (e < E) {
        int p = atomicAdd(&cursor[tgti[e]], 1);
        csr_eid[p] = e;
    }
}

// Positional src/tgt arrays in CSR (target-sorted) order.
__global__ __launch_bounds__(256) void permidx_k(const int* __restrict__ csr_eid,
                                                 const int* __restrict__ srcj,
                                                 const int* __restrict__ tgti,
                                                 int* __restrict__ srcp,
                                                 int* __restrict__ tgtp, int E)
{
    int p = blockIdx.x * 256 + threadIdx.x;
    if (p < E) {
        int e = csr_eid[p];
        srcp[p] = srcj[e];
        tgtp[p] = tgti[e];
    }
}

// Boundary fixup after fused-aggregation edge_step: nodes whose CSR segment
// crosses a 32-position window boundary were accumulated via fp32 atomics in
// nfx — convert to bf16 and re-zero. deg-0 nodes get nf=0.
__global__ __launch_bounds__(256) void fixup_k(const int* __restrict__ row_ptr,
                                               float* __restrict__ nfx,
                                               unsigned short* __restrict__ nf_out, int N)
{
    int n = blockIdx.x * 2 + (threadIdx.x >> 7);
    int c = threadIdx.x & 127;
    if (n >= N) return;
    int beg = row_ptr[n], end = row_ptr[n + 1];
    if (beg == end) { nf_out[(size_t)n * ND + c] = 0; return; }
    if ((beg >> 5) != ((end - 1) >> 5)) {
        size_t idx = (size_t)n * ND + c;
        nf_out[idx] = f2bf(nfx[idx]);
        nfx[idx] = 0.f;
    }
}

// One-time weight prep: transpose + fp32->bf16 (+ zero-pad K for edge-embed L1).
__global__ __launch_bounds__(256) void wprep_k(
    const float* __restrict__ mew0, const float* __restrict__ mew1, const float* __restrict__ mnw0,
    const float* __restrict__ eew0, const float* __restrict__ eew1, const float* __restrict__ cw0,
    const float* __restrict__ new0, const float* __restrict__ new1,
    unsigned short* __restrict__ w0T, unsigned short* __restrict__ w1T,
    unsigned short* __restrict__ wmT, unsigned short* __restrict__ w0eT,
    unsigned short* __restrict__ w1eT, unsigned short* __restrict__ cw0T,
    unsigned short* __restrict__ w0nT, unsigned short* __restrict__ w1nT)
{
    int idx = blockIdx.x * 256 + threadIdx.x;
    if (idx < 49152) {
        int c = idx / 768, k = idx % 768;
        w0T[idx] = f2bf(mew0[k * 64 + c]);
    } else if (idx < 57344) {
        int j = idx - 49152; int c = j / 64, k = j % 64;
        w1T[j] = f2bf(mew1[k * 128 + c]);
    } else if (idx < 106496) {
        int j = idx - 57344; int c = j / 384, k = j % 384;
        wmT[j] = f2bf(mnw0[k * 128 + c]);
    } else if (idx < 126976) {
        int j = idx - 106496; int c = j / KPAD, k = j % KPAD;
        w0eT[j] = (k < EIN) ? f2bf(eew0[k * 64 + c]) : (unsigned short)0;
    } else if (idx < 135168) {
        int j = idx - 126976; int c = j / 64, k = j % 64;
        w1eT[j] = f2bf(eew1[k * 128 + c]);
    } else if (idx < 143360) {
        int j = idx - 135168; int c = j / 128, k = j % 128;
        cw0T[j] = f2bf(cw0[k * 64 + c]);
    } else if (idx < 159744) {
        int j = idx - 143360; int c = j / 128, k = j % 128;
        w0nT[j] = f2bf(new0[k * 128 + c]);
    } else if (idx < 176128) {
        int j = idx - 159744; int c = j / 128, k = j % 128;
        w1nT[j] = f2bf(new1[k * 128 + c]);
    }
}

// MFMA node embed: 32 nodes/block (unchanged; writes nf0 + nfA).
__global__ __launch_bounds__(256) void node_embed_k(
    const float* __restrict__ x,
    const unsigned short* __restrict__ w0nT, const float* __restrict__ b0,
    const unsigned short* __restrict__ w1nT, const float* __restrict__ b1,
    unsigned short* __restrict__ nf0_bf, unsigned short* __restrict__ nf_bf, int N)
{
    const int t = threadIdx.x;
    const int n0 = blockIdx.x * TM;
    __shared__ unsigned short wreg[8192];
    __shared__ unsigned short xin[TM][130];
    __shared__ unsigned short h_bf[TM][130];

#pragma unroll
    for (int it = 0; it < 4; it++) {
        int idx = it * 256 + t;
        int r = idx >> 5, c4 = idx & 31;
        int node = n0 + r; if (node >= N) node = N - 1;
        float4 v = *(const float4*)(x + (size_t)node * NIN + c4 * 4);
        unsigned lo = (unsigned)f2bf(v.x) | ((unsigned)f2bf(v.y) << 16);
        unsigned hi = (unsigned)f2bf(v.z) | ((unsigned)f2bf(v.w) << 16);
        *(uint2*)&xin[r][c4 * 4] = make_uint2(lo, hi);
    }

    const int w = t >> 6, lane = t & 63, quad = lane >> 4, n16 = lane & 15;
    const int m = w & 1, nh = w >> 1;

    float4_ acc[4];
#pragma unroll
    for (int q = 0; q < 4; q++) acc[q] = (float4_){0.f, 0.f, 0.f, 0.f};
#pragma unroll
    for (int hf = 0; hf < 2; hf++) {
        stage_frags<8, 2, 128>(w0nT, wreg, t, hf * 64);
        __syncthreads();
#pragma unroll
        for (int kc = 0; kc < 2; kc++) {
            short8 a = *(const short8*)&xin[m * 16 + n16][hf * 64 + kc * 32 + quad * 8];
#pragma unroll
            for (int tt = 0; tt < 4; tt++) {
                short8 b = FRAG(wreg, (nh * 4 + tt) * 2 + kc, lane);
                acc[tt] = __builtin_amdgcn_mfma_f32_16x16x32_bf16(a, b, acc[tt], 0, 0, 0);
            }
        }
        __syncthreads();
    }
#pragma unroll
    for (int tt = 0; tt < 4; tt++) {
        int c = nh * 64 + tt * 16 + n16;
        float bias = b0[c];
#pragma unroll
        for (int r4 = 0; r4 < 4; r4++)
            h_bf[m * 16 + quad * 4 + r4][c] = f2bf(fmaxf(acc[tt][r4] + bias, 0.f));
    }
    __syncthreads();

    float4_ acc2[4];
#pragma unroll
    for (int q = 0; q < 4; q++) acc2[q] = (float4_){0.f, 0.f, 0.f, 0.f};
#pragma unroll
    for (int hf = 0; hf < 2; hf++) {
        stage_frags<8, 2, 128>(w1nT, wreg, t, hf * 64);
        __syncthreads();
#pragma unroll
        for (int kc = 0; kc < 2; kc++) {
            short8 a = *(const short8*)&h_bf[m * 16 + n16][hf * 64 + kc * 32 + quad * 8];
#pragma unroll
            for (int tt = 0; tt < 4; tt++) {
                short8 b = FRAG(wreg, (nh * 4 + tt) * 2 + kc, lane);
                acc2[tt] = __builtin_amdgcn_mfma_f32_16x16x32_bf16(a, b, acc2[tt], 0, 0, 0);
            }
        }
        __syncthreads();
    }
#pragma unroll
    for (int tt = 0; tt < 4; tt++) {
        int c = nh * 64 + tt * 16 + n16;
        float bias = b1[c];
#pragma unroll
        for (int r4 = 0; r4 < 4; r4++) {
            int row = m * 16 + quad * 4 + r4;
            int node = n0 + row;
            if (node < N) {
                unsigned short v = f2bf(acc2[tt][r4] + bias);
                nf0_bf[(size_t)node * ND + c] = v;
                nf_bf[(size_t)node * ND + c] = v;
            }
        }
    }
}

// MFMA edge embed (co-resident 768 blocks, 3 tiles each) + CSR-permuted rows.
__global__ __launch_bounds__(256, 3) void edge_embed_k(
    const float* __restrict__ ea, const int* __restrict__ csr_eid,
    const unsigned short* __restrict__ w0eT, const float* __restrict__ b0,
    const unsigned short* __restrict__ w1eT, const float* __restrict__ b1,
    unsigned short* __restrict__ ef0_bf, unsigned short* __restrict__ ef_bf,
    int E, int ntiles)
{
    const int t = threadIdx.x;
    __shared__ unsigned short w0reg[10240];   // 20KB: one K-half (T=4, KC=5)
    __shared__ unsigned short w1reg[8192];    // 16KB: w1e full (T=8, KC=2)
    __shared__ unsigned short hsl[4][16 * 66];

    const int w = t >> 6, lane = t & 63, quad = lane >> 4, n16 = lane & 15;

    stage_frags<8, 2, 64>(w1eT, w1reg, t, 0);   // covered by first barrier below

    int ng = 0;
    int tile[MAXGE];
#pragma unroll
    for (int g = 0; g < MAXGE; g++) {
        int tl = blockIdx.x + g * GSE;
        if (tl < ntiles) { tile[g] = tl; ng = g + 1; }
        else tile[g] = 0;
    }

    float4_ accL[MAXGE][4];
#pragma unroll
    for (int g = 0; g < MAXGE; g++)
#pragma unroll
        for (int q = 0; q < 4; q++) accL[g][q] = (float4_){0.f, 0.f, 0.f, 0.f};

#pragma unroll
    for (int hf = 0; hf < 2; hf++) {
        __syncthreads();
        stage_frags<4, 5, KPAD>(w0eT, w0reg, t, hf * 160);
        __syncthreads();
#pragma unroll
        for (int g = 0; g < MAXGE; g++) {
            if (g < ng) {
                int p = tile[g] * 64 + w * 16 + n16; if (p >= E) p = E - 1;
                const float* src = ea + (size_t)csr_eid[p] * EIN;
#pragma unroll
                for (int kc = 0; kc < 5; kc++) {
                    int k = hf * 160 + kc * 32 + quad * 8;
                    union { short8 s; uint4 u; } av;
                    if (k + 8 <= EIN) {
                        float4 v0 = *(const float4*)(src + k);
                        float4 v1 = *(const float4*)(src + k + 4);
                        av.u.x = (unsigned)f2bf(v0.x) | ((unsigned)f2bf(v0.y) << 16);
                        av.u.y = (unsigned)f2bf(v0.z) | ((unsigned)f2bf(v0.w) << 16);
                        av.u.z = (unsigned)f2bf(v1.x) | ((unsigned)f2bf(v1.y) << 16);
                        av.u.w = (unsigned)f2bf(v1.z) | ((unsigned)f2bf(v1.w) << 16);
                    } else {
                        unsigned short vv[8];
#pragma unroll
                        for (int j = 0; j < 8; j++)
                            vv[j] = (k + j < EIN) ? f2bf(src[k + j]) : (unsigned short)0;
                        av.u.x = (unsigned)vv[0] | ((unsigned)vv[1] << 16);
                        av.u.y = (unsigned)vv[2] | ((unsigned)vv[3] << 16);
                        av.u.z = (unsigned)vv[4] | ((unsigned)vv[5] << 16);
                        av.u.w = (unsigned)vv[6] | ((unsigned)vv[7] << 16);
                    }
#pragma unroll
                    for (int tt = 0; tt < 4; tt++) {
                        short8 b = FRAG(w0reg, tt * 5 + kc, lane);
                        accL[g][tt] = __builtin_amdgcn_mfma_f32_16x16x32_bf16(av.s, b, accL[g][tt], 0, 0, 0);
                    }
                }
            }
        }
    }

    // epilogue per tile: bias+ReLU -> per-wave hsl (C->A transform), then L2
#pragma unroll
    for (int g = 0; g < MAXGE; g++) {
        if (g < ng) {
#pragma unroll
            for (int tt = 0; tt < 4; tt++) {
                int c = tt * 16 + n16;
                float bias = b0[c];
#pragma unroll
                for (int r4 = 0; r4 < 4; r4++)
                    hsl[w][(quad * 4 + r4) * 66 + c] = f2bf(fmaxf(accL[g][tt][r4] + bias, 0.f));
            }
            float4_ acc2[8];
#pragma unroll
            for (int q = 0; q < 8; q++) acc2[q] = (float4_){0.f, 0.f, 0.f, 0.f};
#pragma unroll
            for (int kc = 0; kc < 2; kc++) {
                short8 a2 = *(const short8*)&hsl[w][n16 * 66 + kc * 32 + quad * 8];
#pragma unroll
                for (int tt = 0; tt < 8; tt++)
                    acc2[tt] = __builtin_amdgcn_mfma_f32_16x16x32_bf16(
                        a2, FRAG(w1reg, tt * 2 + kc, lane), acc2[tt], 0, 0, 0);
            }
#pragma unroll
            for (int tt = 0; tt < 8; tt++) {
                int c = tt * 16 + n16;
                float bias = b1[c];
#pragma unroll
                for (int r4 = 0; r4 < 4; r4++) {
                    int p = tile[g] * 64 + w * 16 + quad * 4 + r4;
                    if (p < E) {
                        unsigned short v = f2bf(acc2[tt][r4] + bias);  // no ReLU
                        ef0_bf[(size_t)p * ED + c] = v;
                        ef_bf[(size_t)p * ED + c] = v;
                    }
                }
            }
        }
    }
}

// MFMA MPN step v6: CSR order + fused aggregation, 16KB weight chunks
// (13 phases) -> LDS 32.6KB -> 4 blocks/CU (launch_bounds(256,4)).
// R12 measured: 32KB chunks at 3 blocks/CU = 100us, latency-bound with 2.03
// sequential block-rounds; 4 blocks/CU cuts rounds to 1.53.
__global__ __launch_bounds__(256, 4) void edge_step_k(
    const int* __restrict__ srcp, const int* __restrict__ tgtp,
    const unsigned short* __restrict__ nf0_bf, const unsigned short* __restrict__ nf_in,
    const unsigned short* __restrict__ ef0_bf, unsigned short* __restrict__ ef_bf,
    unsigned short* __restrict__ nf_out, float* __restrict__ nfx,
    const unsigned short* __restrict__ w0T, const float* __restrict__ meb0,
    const unsigned short* __restrict__ w1T, const float* __restrict__ meb1,
    const unsigned short* __restrict__ wmT, const float* __restrict__ mnb0,
    int E, int wmsg)
{
    const int t = threadIdx.x;
    const int e0 = blockIdx.x * TS;
    __shared__ unsigned short wreg[8192];      // 16KB weight staging / msg tile [64][128]
    __shared__ unsigned short hef[4][2080];    // per-wave band: h(66) then efn(130)

    const int w = t >> 6, lane = t & 63, quad = lane >> 4, n16 = lane & 15;
    int ec = e0 + w * 16 + n16; if (ec >= E) ec = E - 1;
    const int ti = tgtp[ec], sj = srcp[ec];

    const unsigned short* pA[6] = {
        nf0_bf + (size_t)ti * ND + quad * 8,
        nf_in  + (size_t)ti * ND + quad * 8,
        nf0_bf + (size_t)sj * ND + quad * 8,
        nf_in  + (size_t)sj * ND + quad * 8,
        ef0_bf + (size_t)ec * ED + quad * 8,
        ef_bf  + (size_t)ec * ED + quad * 8 };

    // ---- edge MLP layer 0: [64x768]x[768->64], K in 6 chunks of 128 ----
    float4_ accL[4];
#pragma unroll
    for (int q = 0; q < 4; q++) accL[q] = (float4_){0.f, 0.f, 0.f, 0.f};
#pragma unroll
    for (int hf = 0; hf < 6; hf++) {
        short8 a4[4];
#pragma unroll
        for (int q2 = 0; q2 < 4; q2++)
            a4[q2] = *(const short8*)(pA[hf] + q2 * 32);
        stage_frags<4, 4, 768>(w0T, wreg, t, hf * 128);
        __syncthreads();
#pragma unroll
        for (int kc = 0; kc < 4; kc++) {
#pragma unroll
            for (int tt = 0; tt < 4; tt++) {
                short8 b = FRAG(wreg, tt * 4 + kc, lane);
                accL[tt] = __builtin_amdgcn_mfma_f32_16x16x32_bf16(a4[kc], b, accL[tt], 0, 0, 0);
            }
        }
        __syncthreads();
    }

    // L0 epilogue -> h in own-wave band (stride 66), no barrier needed
#pragma unroll
    for (int tt = 0; tt < 4; tt++) {
        int c = tt * 16 + n16;
        float bias = meb0[c];
#pragma unroll
        for (int r4 = 0; r4 < 4; r4++)
            hef[w][(quad * 4 + r4) * 66 + c] = f2bf(fmaxf(accL[tt][r4] + bias, 0.f));
    }

    // ---- edge MLP layer 1: [64x64]x[64->128] ----
    stage_frags<8, 2, 64>(w1T, wreg, t, 0);    // 16KB into wreg
    __syncthreads();
    {
        float4_ acc[8];
#pragma unroll
        for (int q = 0; q < 8; q++) acc[q] = (float4_){0.f, 0.f, 0.f, 0.f};
#pragma unroll
        for (int kc = 0; kc < 2; kc++) {
            short8 a = *(const short8*)&hef[w][n16 * 66 + kc * 32 + quad * 8];
#pragma unroll
            for (int tt = 0; tt < 8; tt++) {
                short8 b = FRAG(wreg, tt * 2 + kc, lane);
                acc[tt] = __builtin_amdgcn_mfma_f32_16x16x32_bf16(a, b, acc[tt], 0, 0, 0);
            }
        }
        // epilogue: efn into own-wave band (stride 130) + global ef store
#pragma unroll
        for (int tt = 0; tt < 8; tt++) {
            int c = tt * 16 + n16;
            float bias = meb1[c];
#pragma unroll
            for (int r4 = 0; r4 < 4; r4++) {
                int row = quad * 4 + r4;
                unsigned short v = f2bf(fmaxf(acc[tt][r4] + bias, 0.f));
                hef[w][row * 130 + c] = v;
                int e = e0 + w * 16 + row;
                if (e < E) ef_bf[(size_t)e * ED + c] = v;
            }
        }
    }
    __syncthreads();

    // ---- node-message MLP: [64x384]x[384->128], K in 6 chunks of 64 ----
    // (skipped on the last step: final nf is never consumed)
    if (wmsg) {
        float4_ accM[8];
#pragma unroll
        for (int q = 0; q < 8; q++) accM[q] = (float4_){0.f, 0.f, 0.f, 0.f};
#pragma unroll
        for (int j = 0; j < 6; j++) {
            short8 a2[2];
#pragma unroll
            for (int kc = 0; kc < 2; kc++) {
                int kk = j * 2 + kc;
                if (kk < 8) a2[kc] = *(const short8*)(pA[kk >> 2] + (kk & 3) * 32);
                else        a2[kc] = *(const short8*)&hef[w][n16 * 130 + (kk - 8) * 32 + quad * 8];
            }
            stage_frags<8, 2, 384>(wmT, wreg, t, j * 64);
            __syncthreads();
#pragma unroll
            for (int kc = 0; kc < 2; kc++) {
#pragma unroll
                for (int tt = 0; tt < 8; tt++) {
                    short8 b = FRAG(wreg, tt * 2 + kc, lane);
                    accM[tt] = __builtin_amdgcn_mfma_f32_16x16x32_bf16(a2[kc], b, accM[tt], 0, 0, 0);
                }
            }
            __syncthreads();
        }

        // ---- fused aggregation ----
        // stash msg tile (bias+ReLU, bf16) into wreg as [64][128]
#pragma unroll
        for (int tt = 0; tt < 8; tt++) {
            int c = tt * 16 + n16;
            float bias = mnb0[c];
#pragma unroll
            for (int r4 = 0; r4 < 4; r4++) {
                int row = w * 16 + quad * 4 + r4;
                wreg[row * 128 + c] = f2bf(fmaxf(accM[tt][r4] + bias, 0.f));
            }
        }
        // stage tgts for p = e0-1 .. e0+64 into int scratch (hef area is free)
        int* tg = (int*)&hef[0][0];
        if (t < 66) {
            int p = e0 - 1 + t;
            tg[t] = (p >= 0 && p < E) ? tgtp[p] : -1;
        }
        __syncthreads();
        {
            int c = t & 127, half = t >> 7;
            int r0 = half * 32;
            float acc = 0.f;
            int rs = 0;
            for (int r = 0; r < 32; r++) {
                int p = e0 + r0 + r;
                if (p >= E) break;
                int n = tg[r0 + r + 1];
                acc += bf2f(wreg[(r0 + r) * 128 + c]);
                bool end_here = (tg[r0 + r + 2] != n);
                if (end_here) {
                    bool beg_in = (rs > 0) || (tg[r0] != n);
                    if (beg_in) nf_out[(size_t)n * ND + c] = f2bf(acc);
                    else        atomicAdd(&nfx[(size_t)n * ND + c], acc);
                    acc = 0.f; rs = r + 1;
                } else if (r == 31) {
                    atomicAdd(&nfx[(size_t)n * ND + c], acc);
                }
            }
        }
    }
}

// classify: computes at CSR position p, scatters to out[csr_eid[p]].
__global__ __launch_bounds__(256) void classify_k(
    const unsigned short* __restrict__ ef_bf, const int* __restrict__ csr_eid,
    const unsigned short* __restrict__ cw0T, const float* __restrict__ cb0,
    const float* __restrict__ cw1, const float* __restrict__ cb1,
    const float* __restrict__ cw2, const float* __restrict__ cb2,
    float* __restrict__ out, int E)
{
    const int t = threadIdx.x;
    const int e0 = blockIdx.x * TM;
    __shared__ unsigned short h0_bf[TM][66];
    __shared__ float h1[TM][33];

    const int w = t >> 6, lane = t & 63, quad = lane >> 4, n16 = lane & 15;
    const int m = w & 1;
    const int erow = m * 16 + n16;
    int ec = e0 + erow; if (ec >= E) ec = E - 1;
    const unsigned short* pa = ef_bf + (size_t)ec * ED + quad * 8;

    {
        const int cb = (w >> 1) * 32;
        float4_ acc0 = {0.f, 0.f, 0.f, 0.f}, acc1 = acc0;
        const unsigned short* b0p = cw0T + (size_t)(cb + n16) * 128 + quad * 8;
        const unsigned short* b1p = b0p + (size_t)16 * 128;
#pragma unroll
        for (int kc = 0; kc < 4; kc++) {
            short8 a  = *(const short8*)(pa + kc * 32);
            short8 bb0 = *(const short8*)(b0p + kc * 32);
            short8 bb1 = *(const short8*)(b1p + kc * 32);
            acc0 = __builtin_amdgcn_mfma_f32_16x16x32_bf16(a, bb0, acc0, 0, 0, 0);
            acc1 = __builtin_amdgcn_mfma_f32_16x16x32_bf16(a, bb1, acc1, 0, 0, 0);
        }
#pragma unroll
        for (int t2 = 0; t2 < 2; t2++) {
            int c = cb + t2 * 16 + n16;
            float bias = cb0[c];
            float4_ ac = t2 ? acc1 : acc0;
#pragma unroll
            for (int r4 = 0; r4 < 4; r4++)
                h0_bf[m * 16 + quad * 4 + r4][c] = f2bf(fmaxf(ac[r4] + bias, 0.f));
        }
    }
    __syncthreads();

    {
        int c = t & 31;
        int rbase = (t >> 5) * 4;
#pragma unroll
        for (int q = 0; q < 4; q++) {
            int r = rbase + q;
            float acc = cb1[c];
#pragma unroll 8
            for (int k = 0; k < 64; k++) acc += bf2f(h0_bf[r][k]) * cw1[k * 32 + c];
            h1[r][c] = fmaxf(acc, 0.f);
        }
    }
    __syncthreads();

    if (t < TM) {
        int p = e0 + t;
        if (p < E) {
            float a = cb2[0];
#pragma unroll
            for (int k = 0; k < 32; k++) a += h1[t][k] * cw2[k];
            out[csr_eid[p]] = a;
        }
    }
}

extern "C" void kernel_launch(void* const* d_in, const int* in_sizes, int n_in,
                              void* d_out, int out_size, void* d_ws, size_t ws_size,
                              hipStream_t stream)
{
    const float* x    = (const float*)d_in[0];
    const float* ea   = (const float*)d_in[1];
    const int*   eidx = (const int*)d_in[2];
    const float* new0 = (const float*)d_in[3];  const float* neb0 = (const float*)d_in[4];
    const float* new1 = (const float*)d_in[5];  const float* neb1 = (const float*)d_in[6];
    const float* eew0 = (const float*)d_in[7];  const float* eeb0 = (const float*)d_in[8];
    const float* eew1 = (const float*)d_in[9];  const float* eeb1 = (const float*)d_in[10];
    const float* mew0 = (const float*)d_in[11]; const float* meb0 = (const float*)d_in[12];
    const float* mew1 = (const float*)d_in[13]; const float* meb1 = (const float*)d_in[14];
    const float* mnw0 = (const float*)d_in[15]; const float* mnb0 = (const float*)d_in[16];
    const float* cw0  = (const float*)d_in[17]; const float* cb0  = (const float*)d_in[18];
    const float* cw1  = (const float*)d_in[19]; const float* cb1  = (const float*)d_in[20];
    const float* cw2  = (const float*)d_in[21]; const float* cb2  = (const float*)d_in[22];

    const int N = in_sizes[0] / NIN;   // 20000
    const int E = in_sizes[2] / 2;     // 100000
    const int* srcj = eidx;            // edge_index[0] = j (source)
    const int* tgti = eidx + E;        // edge_index[1] = i (target)

    char* wsb = (char*)d_ws;
    unsigned short* nf0_bf = (unsigned short*)wsb;          // N*ND
    unsigned short* nfA    = nf0_bf + (size_t)N * ND;       // N*ND (read buf)
    unsigned short* ef0_bf = nfA + (size_t)N * ND;
    unsigned short* ef_bf  = ef0_bf + (size_t)E * ED;
    // former msg slot (E*ND shorts = 25.6MB) now holds nfB (5.1MB) + nfx (10.2MB)
    unsigned short* slot   = ef_bf + (size_t)E * ED;
    unsigned short* nfB    = slot;                          // N*ND bf16 (write buf)
    float*          nfx    = (float*)(slot + (size_t)N * ND); // N*ND fp32 atomics
    unsigned short* w0T  = slot + (size_t)E * ND;           // [64][768]
    unsigned short* w1T  = w0T + 49152;                     // [128][64]
    unsigned short* wmT  = w1T + 8192;                      // [128][384]
    unsigned short* w0eT = wmT + 49152;                     // [64][KPAD]
    unsigned short* w1eT = w0eT + 64 * KPAD;                // [128][64]
    unsigned short* cw0T = w1eT + 8192;                     // [64][128]
    unsigned short* w0nT = cw0T + 8192;                     // [128][128]
    unsigned short* w1nT = w0nT + 16384;                    // [128][128]
    int* deg     = (int*)(w1nT + 16384);                    // N
    int* cursor  = deg + N;                                 // N (contiguous w/ deg)
    int* row_ptr = cursor + N;                              // N+1
    int* csr_eid = row_ptr + (N + 4);                       // E
    int* srcp    = csr_eid + E;                             // E (CSR-order source)
    int* tgtp    = srcp + E;                                // E (CSR-order target, sorted)

    const int eblocks32 = (E + TM - 1) / TM;
    const int nblocks32 = (N + TM - 1) / TM;
    const int ntiles64 = (E + 63) / 64;

    wprep_k<<<(176128 + 255) / 256, 256, 0, stream>>>(mew0, mew1, mnw0, eew0, eew1, cw0,
                                                      new0, new1,
                                                      w0T, w1T, wmT, w0eT, w1eT, cw0T,
                                                      w0nT, w1nT);

    // CSR build (edge_index is constant across all 4 steps)
    zero_k<<<((2 * N) / 4 + 255) / 256, 256, 0, stream>>>((float*)deg, (2 * N) / 4);
    hist_k<<<(E + 255) / 256, 256, 0, stream>>>(tgti, deg, E);
    scan_k<<<1, 256, 0, stream>>>(deg, row_ptr, cursor, N, E);
    scatter_k<<<(E + 255) / 256, 256, 0, stream>>>(tgti, cursor, csr_eid, E);
    permidx_k<<<(E + 255) / 256, 256, 0, stream>>>(csr_eid, srcj, tgti, srcp, tgtp, E);

    // zero the fp32 atomic buffer once (fixup re-zeroes what it uses)
    zero_k<<<((N * ND) / 4 + 255) / 256, 256, 0, stream>>>(nfx, (N * ND) / 4);

    node_embed_k<<<nblocks32, 256, 0, stream>>>(x, w0nT, neb0, w1nT, neb1,
                                                nf0_bf, nfA, N);
    edge_embed_k<<<GSE, 256, 0, stream>>>(ea, csr_eid, w0eT, eeb0, w1eT, eeb1,
                                          ef0_bf, ef_bf, E, ntiles64);

    unsigned short* nfR = nfA;
    unsigned short* nfW = nfB;
    for (int s = 0; s < 4; s++) {
        edge_step_k<<<ntiles64, 256, 0, stream>>>(srcp, tgtp, nf0_bf, nfR,
                                                  ef0_bf, ef_bf, nfW, nfx,
                                                  w0T, meb0, w1T, meb1, wmT, mnb0,
                                                  E, (s < 3) ? 1 : 0);
        if (s < 3) {
            fixup_k<<<(N + 1) / 2, 256, 0, stream>>>(row_ptr, nfx, nfW, N);
            unsigned short* tmp = nfR; nfR = nfW; nfW = tmp;
        }
    }

    classify_k<<<eblocks32, 256, 0, stream>>>(ef_bf, csr_eid, cw0T, cb0, cw1, cb1, cw2, cb2,
                                              (float*)d_out, E);
}

// Round 14
// 645.184 us; speedup vs baseline: 1.4411x; 1.0292x over previous
//
#include <hip/hip_runtime.h>
#include <hip/hip_bf16.h>

#define ND 128
#define ED 128
#define NIN 128
#define EIN 291
#define KPAD 320   // EIN padded to multiple of 32 (w0eT row stride)
#define HH 64
#define TM 32      // nodes per block in node-embed / edges per block in classify
#define TS 64      // edges per block in edge_step
#define GSE 768    // grid blocks for edge_embed part (3 per CU)
#define MAXGE 3    // max 64-edge tiles per edge_embed block

typedef __attribute__((ext_vector_type(8))) short short8;
typedef __attribute__((ext_vector_type(4))) float float4_;

__device__ __forceinline__ unsigned short f2bf(float f)
{
    union { float f; unsigned u; } v; v.f = f;
    unsigned u = v.u;
    unsigned r = (u + 0x7FFFu + ((u >> 16) & 1u)) >> 16;  // RNE
    return (unsigned short)r;
}
__device__ __forceinline__ float bf2f(unsigned short s)
{
    union { unsigned u; float f; } v; v.u = ((unsigned)s) << 16;
    return v.f;
}

// Stage T N-tiles x KC k-chunks of B (layout [col][K], bf16) into LDS in MFMA
// FRAGMENT ORDER: fragment f=tt*KC+kc occupies 64 consecutive short8 slots.
template<int T, int KC, int K>
__device__ __forceinline__ void stage_frags(const unsigned short* __restrict__ src,
                                            unsigned short* __restrict__ wreg,
                                            int t, int k0)
{
    constexpr int TOT = T * KC * 64;
#pragma unroll
    for (int it = 0; it < TOT / 256; it++) {
        int idx = it * 256 + t;
        int f = idx >> 6, l = idx & 63;
        int col = (f / KC) * 16 + (l & 15);
        int k = (f % KC) * 32 + ((l >> 4) * 8);
        *(short8*)&wreg[idx * 8] = *(const short8*)&src[(size_t)col * K + k0 + k];
    }
}
#define FRAG(wreg, f, lane) (*(const short8*)&(wreg)[(((f) << 6) + (lane)) * 8])

// Zero a buffer (16B granules).
__global__ __launch_bounds__(256) void zero_k(float* __restrict__ p, int n4)
{
    int idx = blockIdx.x * 256 + threadIdx.x;
    if (idx < n4) ((float4*)p)[idx] = make_float4(0.f, 0.f, 0.f, 0.f);
}

// ---- CSR build (once per launch; edge_index is constant across the 4 steps) ----
__global__ __launch_bounds__(256) void hist_k(const int* __restrict__ tgti,
                                              int* __restrict__ deg, int E)
{
    int e = blockIdx.x * 256 + threadIdx.x;
    if (e < E) atomicAdd(&deg[tgti[e]], 1);
}

// Single-block exclusive scan over deg[0..N) -> row_ptr & cursor.
__global__ __launch_bounds__(256) void scan_k(const int* __restrict__ deg,
                                              int* __restrict__ row_ptr,
                                              int* __restrict__ cursor, int N, int E)
{
    __shared__ int part[256];
    const int t = threadIdx.x;
    const int chunk = (N + 255) / 256;
    const int base = t * chunk;
    int s = 0;
    for (int k = 0; k < chunk; k++) { int idx = base + k; if (idx < N) s += deg[idx]; }
    part[t] = s;
    __syncthreads();
    for (int off = 1; off < 256; off <<= 1) {
        int v = (t >= off) ? part[t - off] : 0;
        __syncthreads();
        part[t] += v;
        __syncthreads();
    }
    int run = (t == 0) ? 0 : part[t - 1];
    for (int k = 0; k < chunk; k++) {
        int idx = base + k;
        if (idx < N) { row_ptr[idx] = run; cursor[idx] = run; run += deg[idx]; }
    }
    if (t == 255) row_ptr[N] = E;
}

// scatter + positional perm fused: writes csr_eid, srcp, tgtp in one pass.
__global__ __launch_bounds__(256) void scatter_k(const int* __restrict__ srcj,
                                                 const int* __restrict__ tgti,
                                                 int* __restrict__ cursor,
                                                 int* __restrict__ csr_eid,
                                                 int* __restrict__ srcp,
                                                 int* __restrict__ tgtp, int E)
{
    int e = blockIdx.x * 256 + threadIdx.x;
    if (e < E) {
        int tg = tgti[e];
        int p = atomicAdd(&cursor[tg], 1);
        csr_eid[p] = e;
        srcp[p] = srcj[e];
        tgtp[p] = tg;
    }
}

// Boundary fixup after fused-aggregation edge_step: nodes whose CSR segment
// crosses a 32-position window boundary were accumulated via fp32 atomics in
// nfx — convert to bf16 and re-zero. deg-0 nodes get nf=0.
__global__ __launch_bounds__(256) void fixup_k(const int* __restrict__ row_ptr,
                                               float* __restrict__ nfx,
                                               unsigned short* __restrict__ nf_out, int N)
{
    int n = blockIdx.x * 2 + (threadIdx.x >> 7);
    int c = threadIdx.x & 127;
    if (n >= N) return;
    int beg = row_ptr[n], end = row_ptr[n + 1];
    if (beg == end) { nf_out[(size_t)n * ND + c] = 0; return; }
    if ((beg >> 5) != ((end - 1) >> 5)) {
        size_t idx = (size_t)n * ND + c;
        nf_out[idx] = f2bf(nfx[idx]);
        nfx[idx] = 0.f;
    }
}

// One-time weight prep: transpose + fp32->bf16 (+ zero-pad K for edge-embed L1).
// Also zeroes deg[] (saves a launch; hist runs after this on the same stream).
__global__ __launch_bounds__(256) void wprep_k(
    const float* __restrict__ mew0, const float* __restrict__ mew1, const float* __restrict__ mnw0,
    const float* __restrict__ eew0, const float* __restrict__ eew1, const float* __restrict__ cw0,
    const float* __restrict__ new0, const float* __restrict__ new1,
    unsigned short* __restrict__ w0T, unsigned short* __restrict__ w1T,
    unsigned short* __restrict__ wmT, unsigned short* __restrict__ w0eT,
    unsigned short* __restrict__ w1eT, unsigned short* __restrict__ cw0T,
    unsigned short* __restrict__ w0nT, unsigned short* __restrict__ w1nT,
    int* __restrict__ deg, int N)
{
    int idx = blockIdx.x * 256 + threadIdx.x;
    if (idx < 49152) {
        int c = idx / 768, k = idx % 768;
        w0T[idx] = f2bf(mew0[k * 64 + c]);
    } else if (idx < 57344) {
        int j = idx - 49152; int c = j / 64, k = j % 64;
        w1T[j] = f2bf(mew1[k * 128 + c]);
    } else if (idx < 106496) {
        int j = idx - 57344; int c = j / 384, k = j % 384;
        wmT[j] = f2bf(mnw0[k * 128 + c]);
    } else if (idx < 126976) {
        int j = idx - 106496; int c = j / KPAD, k = j % KPAD;
        w0eT[j] = (k < EIN) ? f2bf(eew0[k * 64 + c]) : (unsigned short)0;
    } else if (idx < 135168) {
        int j = idx - 126976; int c = j / 64, k = j % 64;
        w1eT[j] = f2bf(eew1[k * 128 + c]);
    } else if (idx < 143360) {
        int j = idx - 135168; int c = j / 128, k = j % 128;
        cw0T[j] = f2bf(cw0[k * 64 + c]);
    } else if (idx < 159744) {
        int j = idx - 143360; int c = j / 128, k = j % 128;
        w0nT[j] = f2bf(new0[k * 128 + c]);
    } else if (idx < 176128) {
        int j = idx - 159744; int c = j / 128, k = j % 128;
        w1nT[j] = f2bf(new1[k * 128 + c]);
    } else if (idx < 176128 + N) {
        deg[idx - 176128] = 0;
    }
}

// FUSED embeds: blocks [0,GSE) run the edge-embed body (co-resident, 3 tiles
// each, CSR-permuted rows); blocks [GSE, GSE+nblocks) run node-embed.
// The two are independent — fusing overlaps their latency instead of
// serializing ~110us of back-to-back dispatches. LDS is a union (45.3KB max).
__global__ __launch_bounds__(256, 3) void embed_k(
    // edge part
    const float* __restrict__ ea, const int* __restrict__ csr_eid,
    const unsigned short* __restrict__ w0eT, const float* __restrict__ eb0,
    const unsigned short* __restrict__ w1eT, const float* __restrict__ eb1,
    unsigned short* __restrict__ ef0_bf, unsigned short* __restrict__ ef_bf,
    int E, int ntiles,
    // node part
    const float* __restrict__ x,
    const unsigned short* __restrict__ w0nT, const float* __restrict__ nb0,
    const unsigned short* __restrict__ w1nT, const float* __restrict__ nb1,
    unsigned short* __restrict__ nf0_bf, unsigned short* __restrict__ nf_bf, int N)
{
    __shared__ unsigned short smem[22656];    // 45.3KB union
    const int t = threadIdx.x;
    const int w = t >> 6, lane = t & 63, quad = lane >> 4, n16 = lane & 15;

    if (blockIdx.x < GSE) {
        // ================= edge embed =================
        unsigned short* w0reg = smem;               // 10240 shorts (20KB)
        unsigned short* w1reg = smem + 10240;       // 8192 shorts (16KB)
        unsigned short* hsl   = smem + 18432;       // 4224 shorts ([4][16*66])

        stage_frags<8, 2, 64>(w1eT, w1reg, t, 0);   // covered by first barrier below

        int ng = 0;
        int tile[MAXGE];
#pragma unroll
        for (int g = 0; g < MAXGE; g++) {
            int tl = blockIdx.x + g * GSE;
            if (tl < ntiles) { tile[g] = tl; ng = g + 1; }
            else tile[g] = 0;
        }

        float4_ accL[MAXGE][4];
#pragma unroll
        for (int g = 0; g < MAXGE; g++)
#pragma unroll
            for (int q = 0; q < 4; q++) accL[g][q] = (float4_){0.f, 0.f, 0.f, 0.f};

#pragma unroll
        for (int hf = 0; hf < 2; hf++) {
            __syncthreads();
            stage_frags<4, 5, KPAD>(w0eT, w0reg, t, hf * 160);
            __syncthreads();
#pragma unroll
            for (int g = 0; g < MAXGE; g++) {
                if (g < ng) {
                    int p = tile[g] * 64 + w * 16 + n16; if (p >= E) p = E - 1;
                    const float* src = ea + (size_t)csr_eid[p] * EIN;
#pragma unroll
                    for (int kc = 0; kc < 5; kc++) {
                        int k = hf * 160 + kc * 32 + quad * 8;
                        union { short8 s; uint4 u; } av;
                        if (k + 8 <= EIN) {
                            float4 v0 = *(const float4*)(src + k);
                            float4 v1 = *(const float4*)(src + k + 4);
                            av.u.x = (unsigned)f2bf(v0.x) | ((unsigned)f2bf(v0.y) << 16);
                            av.u.y = (unsigned)f2bf(v0.z) | ((unsigned)f2bf(v0.w) << 16);
                            av.u.z = (unsigned)f2bf(v1.x) | ((unsigned)f2bf(v1.y) << 16);
                            av.u.w = (unsigned)f2bf(v1.z) | ((unsigned)f2bf(v1.w) << 16);
                        } else {
                            unsigned short vv[8];
#pragma unroll
                            for (int j = 0; j < 8; j++)
                                vv[j] = (k + j < EIN) ? f2bf(src[k + j]) : (unsigned short)0;
                            av.u.x = (unsigned)vv[0] | ((unsigned)vv[1] << 16);
                            av.u.y = (unsigned)vv[2] | ((unsigned)vv[3] << 16);
                            av.u.z = (unsigned)vv[4] | ((unsigned)vv[5] << 16);
                            av.u.w = (unsigned)vv[6] | ((unsigned)vv[7] << 16);
                        }
#pragma unroll
                        for (int tt = 0; tt < 4; tt++) {
                            short8 b = FRAG(w0reg, tt * 5 + kc, lane);
                            accL[g][tt] = __builtin_amdgcn_mfma_f32_16x16x32_bf16(av.s, b, accL[g][tt], 0, 0, 0);
                        }
                    }
                }
            }
        }

        // epilogue per tile: bias+ReLU -> per-wave hsl (C->A transform), then L2
#pragma unroll
        for (int g = 0; g < MAXGE; g++) {
            if (g < ng) {
#pragma unroll
                for (int tt = 0; tt < 4; tt++) {
                    int c = tt * 16 + n16;
                    float bias = eb0[c];
#pragma unroll
                    for (int r4 = 0; r4 < 4; r4++)
                        hsl[w * 1056 + (quad * 4 + r4) * 66 + c] = f2bf(fmaxf(accL[g][tt][r4] + bias, 0.f));
                }
                float4_ acc2[8];
#pragma unroll
                for (int q = 0; q < 8; q++) acc2[q] = (float4_){0.f, 0.f, 0.f, 0.f};
#pragma unroll
                for (int kc = 0; kc < 2; kc++) {
                    short8 a2 = *(const short8*)&hsl[w * 1056 + n16 * 66 + kc * 32 + quad * 8];
#pragma unroll
                    for (int tt = 0; tt < 8; tt++)
                        acc2[tt] = __builtin_amdgcn_mfma_f32_16x16x32_bf16(
                            a2, FRAG(w1reg, tt * 2 + kc, lane), acc2[tt], 0, 0, 0);
                }
#pragma unroll
                for (int tt = 0; tt < 8; tt++) {
                    int c = tt * 16 + n16;
                    float bias = eb1[c];
#pragma unroll
                    for (int r4 = 0; r4 < 4; r4++) {
                        int p = tile[g] * 64 + w * 16 + quad * 4 + r4;
                        if (p < E) {
                            unsigned short v = f2bf(acc2[tt][r4] + bias);  // no ReLU
                            ef0_bf[(size_t)p * ED + c] = v;
                            ef_bf[(size_t)p * ED + c] = v;
                        }
                    }
                }
            }
        }
    } else {
        // ================= node embed =================
        unsigned short* wreg = smem;                // 8192 shorts (16KB)
        unsigned short* xin  = smem + 8192;         // [32][130]
        unsigned short* h_bf = smem + 12352;        // [32][130]
        const int n0 = (blockIdx.x - GSE) * TM;

#pragma unroll
        for (int it = 0; it < 4; it++) {
            int idx = it * 256 + t;
            int r = idx >> 5, c4 = idx & 31;
            int node = n0 + r; if (node >= N) node = N - 1;
            float4 v = *(const float4*)(x + (size_t)node * NIN + c4 * 4);
            unsigned lo = (unsigned)f2bf(v.x) | ((unsigned)f2bf(v.y) << 16);
            unsigned hi = (unsigned)f2bf(v.z) | ((unsigned)f2bf(v.w) << 16);
            *(uint2*)&xin[r * 130 + c4 * 4] = make_uint2(lo, hi);
        }

        const int m = w & 1, nh = w >> 1;

        float4_ acc[4];
#pragma unroll
        for (int q = 0; q < 4; q++) acc[q] = (float4_){0.f, 0.f, 0.f, 0.f};
#pragma unroll
        for (int hf = 0; hf < 2; hf++) {
            stage_frags<8, 2, 128>(w0nT, wreg, t, hf * 64);
            __syncthreads();
#pragma unroll
            for (int kc = 0; kc < 2; kc++) {
                short8 a = *(const short8*)&xin[(m * 16 + n16) * 130 + hf * 64 + kc * 32 + quad * 8];
#pragma unroll
                for (int tt = 0; tt < 4; tt++) {
                    short8 b = FRAG(wreg, (nh * 4 + tt) * 2 + kc, lane);
                    acc[tt] = __builtin_amdgcn_mfma_f32_16x16x32_bf16(a, b, acc[tt], 0, 0, 0);
                }
            }
            __syncthreads();
        }
#pragma unroll
        for (int tt = 0; tt < 4; tt++) {
            int c = nh * 64 + tt * 16 + n16;
            float bias = nb0[c];
#pragma unroll
            for (int r4 = 0; r4 < 4; r4++)
                h_bf[(m * 16 + quad * 4 + r4) * 130 + c] = f2bf(fmaxf(acc[tt][r4] + bias, 0.f));
        }
        __syncthreads();

        float4_ acc2[4];
#pragma unroll
        for (int q = 0; q < 4; q++) acc2[q] = (float4_){0.f, 0.f, 0.f, 0.f};
#pragma unroll
        for (int hf = 0; hf < 2; hf++) {
            stage_frags<8, 2, 128>(w1nT, wreg, t, hf * 64);
            __syncthreads();
#pragma unroll
            for (int kc = 0; kc < 2; kc++) {
                short8 a = *(const short8*)&h_bf[(m * 16 + n16) * 130 + hf * 64 + kc * 32 + quad * 8];
#pragma unroll
                for (int tt = 0; tt < 4; tt++) {
                    short8 b = FRAG(wreg, (nh * 4 + tt) * 2 + kc, lane);
                    acc2[tt] = __builtin_amdgcn_mfma_f32_16x16x32_bf16(a, b, acc2[tt], 0, 0, 0);
                }
            }
            __syncthreads();
        }
#pragma unroll
        for (int tt = 0; tt < 4; tt++) {
            int c = nh * 64 + tt * 16 + n16;
            float bias = nb1[c];
#pragma unroll
            for (int r4 = 0; r4 < 4; r4++) {
                int row = m * 16 + quad * 4 + r4;
                int node = n0 + row;
                if (node < N) {
                    unsigned short v = f2bf(acc2[tt][r4] + bias);
                    nf0_bf[(size_t)node * ND + c] = v;
                    nf_bf[(size_t)node * ND + c] = v;
                }
            }
        }
    }
}

// MFMA MPN step v6: CSR order + fused aggregation, 16KB weight chunks
// (13 phases) -> LDS 32.6KB -> 4 blocks/CU (launch_bounds(256,4)).
__global__ __launch_bounds__(256, 4) void edge_step_k(
    const int* __restrict__ srcp, const int* __restrict__ tgtp,
    const unsigned short* __restrict__ nf0_bf, const unsigned short* __restrict__ nf_in,
    const unsigned short* __restrict__ ef0_bf, unsigned short* __restrict__ ef_bf,
    unsigned short* __restrict__ nf_out, float* __restrict__ nfx,
    const unsigned short* __restrict__ w0T, const float* __restrict__ meb0,
    const unsigned short* __restrict__ w1T, const float* __restrict__ meb1,
    const unsigned short* __restrict__ wmT, const float* __restrict__ mnb0,
    int E, int wmsg)
{
    const int t = threadIdx.x;
    const int e0 = blockIdx.x * TS;
    __shared__ unsigned short wreg[8192];      // 16KB weight staging / msg tile [64][128]
    __shared__ unsigned short hef[4][2080];    // per-wave band: h(66) then efn(130)

    const int w = t >> 6, lane = t & 63, quad = lane >> 4, n16 = lane & 15;
    int ec = e0 + w * 16 + n16; if (ec >= E) ec = E - 1;
    const int ti = tgtp[ec], sj = srcp[ec];

    const unsigned short* pA[6] = {
        nf0_bf + (size_t)ti * ND + quad * 8,
        nf_in  + (size_t)ti * ND + quad * 8,
        nf0_bf + (size_t)sj * ND + quad * 8,
        nf_in  + (size_t)sj * ND + quad * 8,
        ef0_bf + (size_t)ec * ED + quad * 8,
        ef_bf  + (size_t)ec * ED + quad * 8 };

    // ---- edge MLP layer 0: [64x768]x[768->64], K in 6 chunks of 128 ----
    float4_ accL[4];
#pragma unroll
    for (int q = 0; q < 4; q++) accL[q] = (float4_){0.f, 0.f, 0.f, 0.f};
#pragma unroll
    for (int hf = 0; hf < 6; hf++) {
        short8 a4[4];
#pragma unroll
        for (int q2 = 0; q2 < 4; q2++)
            a4[q2] = *(const short8*)(pA[hf] + q2 * 32);
        stage_frags<4, 4, 768>(w0T, wreg, t, hf * 128);
        __syncthreads();
#pragma unroll
        for (int kc = 0; kc < 4; kc++) {
#pragma unroll
            for (int tt = 0; tt < 4; tt++) {
                short8 b = FRAG(wreg, tt * 4 + kc, lane);
                accL[tt] = __builtin_amdgcn_mfma_f32_16x16x32_bf16(a4[kc], b, accL[tt], 0, 0, 0);
            }
        }
        __syncthreads();
    }

    // L0 epilogue -> h in own-wave band (stride 66), no barrier needed
#pragma unroll
    for (int tt = 0; tt < 4; tt++) {
        int c = tt * 16 + n16;
        float bias = meb0[c];
#pragma unroll
        for (int r4 = 0; r4 < 4; r4++)
            hef[w][(quad * 4 + r4) * 66 + c] = f2bf(fmaxf(accL[tt][r4] + bias, 0.f));
    }

    // ---- edge MLP layer 1: [64x64]x[64->128] ----
    stage_frags<8, 2, 64>(w1T, wreg, t, 0);    // 16KB into wreg
    __syncthreads();
    {
        float4_ acc[8];
#pragma unroll
        for (int q = 0; q < 8; q++) acc[q] = (float4_){0.f, 0.f, 0.f, 0.f};
#pragma unroll
        for (int kc = 0; kc < 2; kc++) {
            short8 a = *(const short8*)&hef[w][n16 * 66 + kc * 32 + quad * 8];
#pragma unroll
            for (int tt = 0; tt < 8; tt++) {
                short8 b = FRAG(wreg, tt * 2 + kc, lane);
                acc[tt] = __builtin_amdgcn_mfma_f32_16x16x32_bf16(a, b, acc[tt], 0, 0, 0);
            }
        }
        // epilogue: efn into own-wave band (stride 130) + global ef store
#pragma unroll
        for (int tt = 0; tt < 8; tt++) {
            int c = tt * 16 + n16;
            float bias = meb1[c];
#pragma unroll
            for (int r4 = 0; r4 < 4; r4++) {
                int row = quad * 4 + r4;
                unsigned short v = f2bf(fmaxf(acc[tt][r4] + bias, 0.f));
                hef[w][row * 130 + c] = v;
                int e = e0 + w * 16 + row;
                if (e < E) ef_bf[(size_t)e * ED + c] = v;
            }
        }
    }
    __syncthreads();

    // ---- node-message MLP: [64x384]x[384->128], K in 6 chunks of 64 ----
    // (skipped on the last step: final nf is never consumed)
    if (wmsg) {
        float4_ accM[8];
#pragma unroll
        for (int q = 0; q < 8; q++) accM[q] = (float4_){0.f, 0.f, 0.f, 0.f};
#pragma unroll
        for (int j = 0; j < 6; j++) {
            short8 a2[2];
#pragma unroll
            for (int kc = 0; kc < 2; kc++) {
                int kk = j * 2 + kc;
                if (kk < 8) a2[kc] = *(const short8*)(pA[kk >> 2] + (kk & 3) * 32);
                else        a2[kc] = *(const short8*)&hef[w][n16 * 130 + (kk - 8) * 32 + quad * 8];
            }
            stage_frags<8, 2, 384>(wmT, wreg, t, j * 64);
            __syncthreads();
#pragma unroll
            for (int kc = 0; kc < 2; kc++) {
#pragma unroll
                for (int tt = 0; tt < 8; tt++) {
                    short8 b = FRAG(wreg, tt * 2 + kc, lane);
                    accM[tt] = __builtin_amdgcn_mfma_f32_16x16x32_bf16(a2[kc], b, accM[tt], 0, 0, 0);
                }
            }
            __syncthreads();
        }

        // ---- fused aggregation ----
        // stash msg tile (bias+ReLU, bf16) into wreg as [64][128]
#pragma unroll
        for (int tt = 0; tt < 8; tt++) {
            int c = tt * 16 + n16;
            float bias = mnb0[c];
#pragma unroll
            for (int r4 = 0; r4 < 4; r4++) {
                int row = w * 16 + quad * 4 + r4;
                wreg[row * 128 + c] = f2bf(fmaxf(accM[tt][r4] + bias, 0.f));
            }
        }
        // stage tgts for p = e0-1 .. e0+64 into int scratch (hef area is free)
        int* tg = (int*)&hef[0][0];
        if (t < 66) {
            int p = e0 - 1 + t;
            tg[t] = (p >= 0 && p < E) ? tgtp[p] : -1;
        }
        __syncthreads();
        {
            int c = t & 127, half = t >> 7;
            int r0 = half * 32;
            float acc = 0.f;
            int rs = 0;
            for (int r = 0; r < 32; r++) {
                int p = e0 + r0 + r;
                if (p >= E) break;
                int n = tg[r0 + r + 1];
                acc += bf2f(wreg[(r0 + r) * 128 + c]);
                bool end_here = (tg[r0 + r + 2] != n);
                if (end_here) {
                    bool beg_in = (rs > 0) || (tg[r0] != n);
                    if (beg_in) nf_out[(size_t)n * ND + c] = f2bf(acc);
                    else        atomicAdd(&nfx[(size_t)n * ND + c], acc);
                    acc = 0.f; rs = r + 1;
                } else if (r == 31) {
                    atomicAdd(&nfx[(size_t)n * ND + c], acc);
                }
            }
        }
    }
}

// classify: computes at CSR position p, scatters to out[csr_eid[p]].
__global__ __launch_bounds__(256) void classify_k(
    const unsigned short* __restrict__ ef_bf, const int* __restrict__ csr_eid,
    const unsigned short* __restrict__ cw0T, const float* __restrict__ cb0,
    const float* __restrict__ cw1, const float* __restrict__ cb1,
    const float* __restrict__ cw2, const float* __restrict__ cb2,
    float* __restrict__ out, int E)
{
    const int t = threadIdx.x;
    const int e0 = blockIdx.x * TM;
    __shared__ unsigned short h0_bf[TM][66];
    __shared__ float h1[TM][33];

    const int w = t >> 6, lane = t & 63, quad = lane >> 4, n16 = lane & 15;
    const int m = w & 1;
    const int erow = m * 16 + n16;
    int ec = e0 + erow; if (ec >= E) ec = E - 1;
    const unsigned short* pa = ef_bf + (size_t)ec * ED + quad * 8;

    {
        const int cb = (w >> 1) * 32;
        float4_ acc0 = {0.f, 0.f, 0.f, 0.f}, acc1 = acc0;
        const unsigned short* b0p = cw0T + (size_t)(cb + n16) * 128 + quad * 8;
        const unsigned short* b1p = b0p + (size_t)16 * 128;
#pragma unroll
        for (int kc = 0; kc < 4; kc++) {
            short8 a  = *(const short8*)(pa + kc * 32);
            short8 bb0 = *(const short8*)(b0p + kc * 32);
            short8 bb1 = *(const short8*)(b1p + kc * 32);
            acc0 = __builtin_amdgcn_mfma_f32_16x16x32_bf16(a, bb0, acc0, 0, 0, 0);
            acc1 = __builtin_amdgcn_mfma_f32_16x16x32_bf16(a, bb1, acc1, 0, 0, 0);
        }
#pragma unroll
        for (int t2 = 0; t2 < 2; t2++) {
            int c = cb + t2 * 16 + n16;
            float bias = cb0[c];
            float4_ ac = t2 ? acc1 : acc0;
#pragma unroll
            for (int r4 = 0; r4 < 4; r4++)
                h0_bf[m * 16 + quad * 4 + r4][c] = f2bf(fmaxf(ac[r4] + bias, 0.f));
        }
    }
    __syncthreads();

    {
        int c = t & 31;
        int rbase = (t >> 5) * 4;
#pragma unroll
        for (int q = 0; q < 4; q++) {
            int r = rbase + q;
            float acc = cb1[c];
#pragma unroll 8
            for (int k = 0; k < 64; k++) acc += bf2f(h0_bf[r][k]) * cw1[k * 32 + c];
            h1[r][c] = fmaxf(acc, 0.f);
        }
    }
    __syncthreads();

    if (t < TM) {
        int p = e0 + t;
        if (p < E) {
            float a = cb2[0];
#pragma unroll
            for (int k = 0; k < 32; k++) a += h1[t][k] * cw2[k];
            out[csr_eid[p]] = a;
        }
    }
}

extern "C" void kernel_launch(void* const* d_in, const int* in_sizes, int n_in,
                              void* d_out, int out_size, void* d_ws, size_t ws_size,
                              hipStream_t stream)
{
    const float* x    = (const float*)d_in[0];
    const float* ea   = (const float*)d_in[1];
    const int*   eidx = (const int*)d_in[2];
    const float* new0 = (const float*)d_in[3];  const float* neb0 = (const float*)d_in[4];
    const float* new1 = (const float*)d_in[5];  const float* neb1 = (const float*)d_in[6];
    const float* eew0 = (const float*)d_in[7];  const float* eeb0 = (const float*)d_in[8];
    const float* eew1 = (const float*)d_in[9];  const float* eeb1 = (const float*)d_in[10];
    const float* mew0 = (const float*)d_in[11]; const float* meb0 = (const float*)d_in[12];
    const float* mew1 = (const float*)d_in[13]; const float* meb1 = (const float*)d_in[14];
    const float* mnw0 = (const float*)d_in[15]; const float* mnb0 = (const float*)d_in[16];
    const float* cw0  = (const float*)d_in[17]; const float* cb0  = (const float*)d_in[18];
    const float* cw1  = (const float*)d_in[19]; const float* cb1  = (const float*)d_in[20];
    const float* cw2  = (const float*)d_in[21]; const float* cb2  = (const float*)d_in[22];

    const int N = in_sizes[0] / NIN;   // 20000
    const int E = in_sizes[2] / 2;     // 100000
    const int* srcj = eidx;            // edge_index[0] = j (source)
    const int* tgti = eidx + E;        // edge_index[1] = i (target)

    char* wsb = (char*)d_ws;
    unsigned short* nf0_bf = (unsigned short*)wsb;          // N*ND
    unsigned short* nfA    = nf0_bf + (size_t)N * ND;       // N*ND (read buf)
    unsigned short* ef0_bf = nfA + (size_t)N * ND;
    unsigned short* ef_bf  = ef0_bf + (size_t)E * ED;
    unsigned short* slot   = ef_bf + (size_t)E * ED;
    unsigned short* nfB    = slot;                          // N*ND bf16 (write buf)
    float*          nfx    = (float*)(slot + (size_t)N * ND); // N*ND fp32 atomics
    unsigned short* w0T  = slot + (size_t)E * ND;           // [64][768]
    unsigned short* w1T  = w0T + 49152;                     // [128][64]
    unsigned short* wmT  = w1T + 8192;                      // [128][384]
    unsigned short* w0eT = wmT + 49152;                     // [64][KPAD]
    unsigned short* w1eT = w0eT + 64 * KPAD;                // [128][64]
    unsigned short* cw0T = w1eT + 8192;                     // [64][128]
    unsigned short* w0nT = cw0T + 8192;                     // [128][128]
    unsigned short* w1nT = w0nT + 16384;                    // [128][128]
    int* deg     = (int*)(w1nT + 16384);                    // N
    int* cursor  = deg + N;                                 // N (contiguous w/ deg)
    int* row_ptr = cursor + N;                              // N+1
    int* csr_eid = row_ptr + (N + 4);                       // E
    int* srcp    = csr_eid + E;                             // E (CSR-order source)
    int* tgtp    = srcp + E;                                // E (CSR-order target, sorted)

    const int eblocks32 = (E + TM - 1) / TM;
    const int nblocks32 = (N + TM - 1) / TM;
    const int ntiles64 = (E + 63) / 64;

    wprep_k<<<(176128 + N + 255) / 256, 256, 0, stream>>>(mew0, mew1, mnw0, eew0, eew1, cw0,
                                                          new0, new1,
                                                          w0T, w1T, wmT, w0eT, w1eT, cw0T,
                                                          w0nT, w1nT, deg, N);

    // CSR build (edge_index is constant across all 4 steps)
    hist_k<<<(E + 255) / 256, 256, 0, stream>>>(tgti, deg, E);
    scan_k<<<1, 256, 0, stream>>>(deg, row_ptr, cursor, N, E);
    scatter_k<<<(E + 255) / 256, 256, 0, stream>>>(srcj, tgti, cursor, csr_eid, srcp, tgtp, E);

    // zero the fp32 atomic buffer once (fixup re-zeroes what it uses)
    zero_k<<<((N * ND) / 4 + 255) / 256, 256, 0, stream>>>(nfx, (N * ND) / 4);

    // fused node+edge embed (independent work overlapped in one dispatch)
    embed_k<<<GSE + nblocks32, 256, 0, stream>>>(ea, csr_eid, w0eT, eeb0, w1eT, eeb1,
                                                 ef0_bf, ef_bf, E, ntiles64,
                                                 x, w0nT, neb0, w1nT, neb1,
                                                 nf0_bf, nfA, N);

    unsigned short* nfR = nfA;
    unsigned short* nfW = nfB;
    for (int s = 0; s < 4; s++) {
        edge_step_k<<<ntiles64, 256, 0, stream>>>(srcp, tgtp, nf0_bf, nfR,
                                                  ef0_bf, ef_bf, nfW, nfx,
                                                  w0T, meb0, w1T, meb1, wmT, mnb0,
                                                  E, (s < 3) ? 1 : 0);
        if (s < 3) {
            fixup_k<<<(N + 1) / 2, 256, 0, stream>>>(row_ptr, nfx, nfW, N);
            unsigned short* tmp = nfR; nfR = nfW; nfW = tmp;
        }
    }

    classify_k<<<eblocks32, 256, 0, stream>>>(ef_bf, csr_eid, cw0T, cb0, cw1, cb1, cw2, cb2,
                                              (float*)d_out, E);
}